// Round 1
// baseline (2314.222 us; speedup 1.0000x reference)
//
#include <hip/hip_runtime.h>
#include <hip/hip_bf16.h>

// ChebConv GNN, N=100000 nodes, E=1600000 directed edges (symmetrized), HID=128, K=4.
// Pipeline: CSR build -> 4x {3 props + GEMM + BN/act}, final L2norm+proj.
// GEMMs (layers 2-4) in bf16 MFMA 16x16x32, everything else fp32.

#define NNODES_EXPECT 100000
#define HID 128
#define NEG 0.01f
#define BN_EPS 1e-5f
#define L2_EPS 1e-12f

typedef __attribute__((ext_vector_type(8))) short short8;
typedef __attribute__((ext_vector_type(4))) float floatx4;

__device__ __forceinline__ short f2bf(float f) {
    unsigned u = __float_as_uint(f);
    return (short)((u + 0x7fffu + ((u >> 16) & 1u)) >> 16);
}

__device__ __forceinline__ float actf(float v, int act) {
    if (act == 0) return v >= 0.f ? v : NEG * v;   // leaky_relu
    if (act == 1) return v > 0.f ? v : 0.f;        // relu
    return v;                                       // none
}

// ---------------- preprocessing ----------------

__global__ __launch_bounds__(256) void k_hist(const int* __restrict__ dst, int* __restrict__ cnt, int E) {
    int e = blockIdx.x * 256 + threadIdx.x;
    if (e < E) atomicAdd(&cnt[dst[e]], 1);
}

__global__ __launch_bounds__(256) void k_dinv(const int* __restrict__ cnt, float* __restrict__ dinv, int N) {
    int i = blockIdx.x * 256 + threadIdx.x;
    if (i < N) {
        int d = cnt[i];
        dinv[i] = d > 0 ? rsqrtf((float)d) : 0.f;
    }
}

// single-block exclusive scan (1024 threads) cnt -> rowptr[0..N], also cursor=rowptr
__global__ __launch_bounds__(1024) void k_scan(const int* __restrict__ cnt, int* __restrict__ rowptr,
                                               int* __restrict__ cursor, int n) {
    __shared__ int wsum[17];
    __shared__ int carry_s;
    int tid = threadIdx.x;
    int lane = tid & 63, w = tid >> 6;
    if (tid == 0) carry_s = 0;
    __syncthreads();
    for (int base = 0; base < n; base += 1024) {
        int i = base + tid;
        int v = (i < n) ? cnt[i] : 0;
        int s = v;
        #pragma unroll
        for (int d = 1; d < 64; d <<= 1) {
            int t = __shfl_up(s, d);
            if (lane >= d) s += t;
        }
        if (lane == 63) wsum[w] = s;
        __syncthreads();
        if (w == 0 && lane < 16) {
            int x = wsum[lane];
            int s2 = x;
            #pragma unroll
            for (int d = 1; d < 16; d <<= 1) {
                int t = __shfl_up(s2, d);
                if (lane >= d) s2 += t;
            }
            wsum[lane] = s2 - x;           // exclusive wave offset
            if (lane == 15) wsum[16] = s2; // block total
        }
        __syncthreads();
        int excl = carry_s + wsum[w] + (s - v);
        if (i < n) { rowptr[i] = excl; cursor[i] = excl; }
        __syncthreads();
        if (tid == 0) carry_s += wsum[16];
    }
    if (tid == 0) rowptr[n] = carry_s;
}

__global__ __launch_bounds__(256) void k_fill(const int* __restrict__ src, const int* __restrict__ dst,
                                              const float* __restrict__ dinv, int* __restrict__ cursor,
                                              int* __restrict__ srcS, float* __restrict__ normS, int E) {
    int e = blockIdx.x * 256 + threadIdx.x;
    if (e >= E) return;
    int s = src[e], d = dst[e];
    int pos = atomicAdd(&cursor[d], 1);
    srcS[pos] = s;
    normS[pos] = -(dinv[s] * dinv[d]);
}

// ---------------- propagation ----------------

// F=3, one thread per node. out = a*prop(T) + b*prev
__global__ __launch_bounds__(256) void k_prop3(const float* __restrict__ T, const float* __restrict__ prev,
                                               float* __restrict__ out, const int* __restrict__ rowptr,
                                               const int* __restrict__ srcS, const float* __restrict__ normS,
                                               float a, float b, int N) {
    int i = blockIdx.x * 256 + threadIdx.x;
    if (i >= N) return;
    float a0 = 0.f, a1 = 0.f, a2 = 0.f;
    int e1 = rowptr[i + 1];
    for (int e = rowptr[i]; e < e1; ++e) {
        int s = srcS[e];
        float w = normS[e];
        a0 += w * T[s * 3 + 0];
        a1 += w * T[s * 3 + 1];
        a2 += w * T[s * 3 + 2];
    }
    float r0 = a * a0, r1 = a * a1, r2 = a * a2;
    if (prev) {
        r0 += b * prev[i * 3 + 0];
        r1 += b * prev[i * 3 + 1];
        r2 += b * prev[i * 3 + 2];
    }
    out[i * 3 + 0] = r0;
    out[i * 3 + 1] = r1;
    out[i * 3 + 2] = r2;
}

// F=128, one wave per node, float2 per lane. out = a*prop(T) + b*prev
__global__ __launch_bounds__(256) void k_prop128(const float* __restrict__ T, const float* __restrict__ prev,
                                                 float* __restrict__ out, const int* __restrict__ rowptr,
                                                 const int* __restrict__ srcS, const float* __restrict__ normS,
                                                 float a, float b, int N) {
    int node = blockIdx.x * 4 + (threadIdx.x >> 6);
    if (node >= N) return;
    node = __builtin_amdgcn_readfirstlane(node);  // wave-uniform -> scalar loads for edge metadata
    int lane = threadIdx.x & 63;
    int e0 = rowptr[node], e1 = rowptr[node + 1];
    float accx = 0.f, accy = 0.f;
    int e = e0;
    for (; e + 1 < e1; e += 2) {
        int s0 = srcS[e], s1 = srcS[e + 1];
        float w0 = normS[e], w1 = normS[e + 1];
        float2 t0 = ((const float2*)T)[(size_t)s0 * 64 + lane];
        float2 t1 = ((const float2*)T)[(size_t)s1 * 64 + lane];
        accx += w0 * t0.x; accy += w0 * t0.y;
        accx += w1 * t1.x; accy += w1 * t1.y;
    }
    if (e < e1) {
        int s0 = srcS[e];
        float w0 = normS[e];
        float2 t0 = ((const float2*)T)[(size_t)s0 * 64 + lane];
        accx += w0 * t0.x; accy += w0 * t0.y;
    }
    float2 r;
    if (prev) {
        float2 p = ((const float2*)prev)[(size_t)node * 64 + lane];
        r.x = a * accx + b * p.x;
        r.y = a * accy + b * p.y;
    } else {
        r.x = a * accx;
        r.y = a * accy;
    }
    ((float2*)out)[(size_t)node * 64 + lane] = r;
}

// ---------------- layer-1 dense (K=12 tiny GEMM) ----------------

__global__ __launch_bounds__(256) void k_gemm1(const float* __restrict__ x, const float* __restrict__ t1,
                                               const float* __restrict__ t2, const float* __restrict__ t3,
                                               const float* __restrict__ W, const float* __restrict__ b,
                                               float* __restrict__ OUT, int N) {
    __shared__ float Wl[12 * 128];
    __shared__ float bl[128];
    int tid = threadIdx.x;
    for (int i = tid; i < 1536; i += 256) Wl[i] = W[i];
    if (tid < 128) bl[tid] = b[tid];
    __syncthreads();
    int node = blockIdx.x * 2 + (tid >> 7);
    if (node >= N) return;
    int f = tid & 127;
    float acc = bl[f];
    const float* rows[4] = {x, t1, t2, t3};
    #pragma unroll
    for (int k = 0; k < 4; ++k) {
        const float* r = rows[k] + (size_t)node * 3;
        acc += r[0] * Wl[(k * 3 + 0) * 128 + f];
        acc += r[1] * Wl[(k * 3 + 1) * 128 + f];
        acc += r[2] * Wl[(k * 3 + 2) * 128 + f];
    }
    OUT[(size_t)node * 128 + f] = acc;
}

// ---------------- big GEMM: OUT[M,128] (+)= [Ta|Tb][M,256] @ Wpacked[256,128] ----------------

// pack W pair (2 x 128x128 fp32) into bf16 B-fragment order:
// flat = ((ks*8+nt)*64+lane)*8+j  ->  B[kk = ks*32 + (lane>>4)*8 + j][c = nt*16 + (lane&15)]
__global__ __launch_bounds__(256) void k_packW(const float* __restrict__ Wa, const float* __restrict__ Wb,
                                               short* __restrict__ Wp) {
    int idx = blockIdx.x * 256 + threadIdx.x;  // 0..32767
    int j = idx & 7;
    int lane = (idx >> 3) & 63;
    int rest = idx >> 9;
    int nt = rest & 7;
    int ks = rest >> 3;
    int kk = ks * 32 + (lane >> 4) * 8 + j;
    int c = nt * 16 + (lane & 15);
    float v = (kk < 128) ? Wa[kk * 128 + c] : Wb[(kk - 128) * 128 + c];
    Wp[idx] = f2bf(v);
}

__global__ __launch_bounds__(256) void k_gemm(const float* __restrict__ Ta, const float* __restrict__ Tb,
                                              const short* __restrict__ Wp, const float* __restrict__ bias,
                                              float* __restrict__ OUT, int M, int withBias, int withAcc) {
    __shared__ short Wlds[32768];  // 64KB: full [256,128] bf16 weight pair, fragment order
    int tid = threadIdx.x;
    for (int i = tid; i < 4096; i += 256) ((int4*)Wlds)[i] = ((const int4*)Wp)[i];
    __syncthreads();
    int lane = tid & 63, wave = tid >> 6;
    int r0 = blockIdx.x * 64 + wave * 16;
    int row = r0 + (lane & 15);
    int quad = lane >> 4;
    int rowc = row < M ? row : M - 1;
    const float* pa = Ta + (size_t)rowc * 128 + quad * 8;
    const float* pb = Tb + (size_t)rowc * 128 + quad * 8;
    floatx4 acc[8];
    #pragma unroll
    for (int i = 0; i < 8; ++i) { acc[i][0] = 0.f; acc[i][1] = 0.f; acc[i][2] = 0.f; acc[i][3] = 0.f; }
    #pragma unroll
    for (int ks = 0; ks < 8; ++ks) {
        const float* p = (ks < 4) ? (pa + ks * 32) : (pb + (ks - 4) * 32);
        float4 v0 = *((const float4*)p);
        float4 v1 = *((const float4*)(p + 4));
        short8 af;
        af[0] = f2bf(v0.x); af[1] = f2bf(v0.y); af[2] = f2bf(v0.z); af[3] = f2bf(v0.w);
        af[4] = f2bf(v1.x); af[5] = f2bf(v1.y); af[6] = f2bf(v1.z); af[7] = f2bf(v1.w);
        #pragma unroll
        for (int nt = 0; nt < 8; ++nt) {
            short8 bf = *((const short8*)(Wlds + ((ks * 8 + nt) * 64 + lane) * 8));
            acc[nt] = __builtin_amdgcn_mfma_f32_16x16x32_bf16(af, bf, acc[nt], 0, 0, 0);
        }
    }
    // C/D layout: col = lane&15, row = quad*4 + reg
    int col0 = lane & 15;
    int rbase = r0 + quad * 4;
    #pragma unroll
    for (int nt = 0; nt < 8; ++nt) {
        int c = nt * 16 + col0;
        float bv = withBias ? bias[c] : 0.f;
        #pragma unroll
        for (int rg = 0; rg < 4; ++rg) {
            int r = rbase + rg;
            if (r < M) {
                size_t idx = (size_t)r * 128 + c;
                float v = acc[nt][rg] + bv;
                if (withAcc) v += OUT[idx];
                OUT[idx] = v;
            }
        }
    }
}

// ---------------- BatchNorm ----------------

__global__ __launch_bounds__(256) void k_stats(const float* __restrict__ X, float* __restrict__ S, int N, int act) {
    int col = threadIdx.x & 127, rh = threadIdx.x >> 7;
    int r0 = blockIdx.x * 512;
    int rend = r0 + 512 < N ? r0 + 512 : N;
    float s1 = 0.f, s2 = 0.f;
    for (int r = r0 + rh; r < rend; r += 2) {
        float v = actf(X[(size_t)r * 128 + col], act);
        s1 += v;
        s2 += v * v;
    }
    atomicAdd(&S[col], s1);
    atomicAdd(&S[col + 128], s2);
}

__global__ __launch_bounds__(128) void k_bnfin(const float* __restrict__ S, const float* __restrict__ g,
                                               const float* __restrict__ be, float* __restrict__ AC, int N) {
    int f = threadIdx.x;
    float mu = S[f] / (float)N;
    float var = S[f + 128] / (float)N - mu * mu;
    float rstd = rsqrtf(var + BN_EPS);
    float a = g[f] * rstd;
    AC[f] = a;
    AC[f + 128] = be[f] - mu * a;
}

__global__ __launch_bounds__(256) void k_bnapply(const float* __restrict__ X, const float* __restrict__ AC,
                                                 float* __restrict__ Y, int n4, int act) {
    int i = blockIdx.x * 256 + threadIdx.x;
    if (i >= n4) return;
    float4 v = ((const float4*)X)[i];
    int col = (i * 4) & 127;
    float4 a = *((const float4*)(AC + col));
    float4 c = *((const float4*)(AC + 128 + col));
    v.x = actf(v.x, act) * a.x + c.x;
    v.y = actf(v.y, act) * a.y + c.y;
    v.z = actf(v.z, act) * a.z + c.z;
    v.w = actf(v.w, act) * a.w + c.w;
    ((float4*)Y)[i] = v;
}

// ---------------- final: L2-normalize rows + project 128->3 ----------------

__global__ __launch_bounds__(256) void k_final(const float* __restrict__ H, const float* __restrict__ Wrep,
                                               const float* __restrict__ brep, float* __restrict__ out, int N) {
    int node = blockIdx.x * 4 + (threadIdx.x >> 6);
    if (node >= N) return;
    int lane = threadIdx.x & 63;
    float2 h = ((const float2*)H)[(size_t)node * 64 + lane];
    int f0 = 2 * lane;
    float nrm = h.x * h.x + h.y * h.y;
    float p0 = h.x * Wrep[f0 * 3 + 0] + h.y * Wrep[(f0 + 1) * 3 + 0];
    float p1 = h.x * Wrep[f0 * 3 + 1] + h.y * Wrep[(f0 + 1) * 3 + 1];
    float p2 = h.x * Wrep[f0 * 3 + 2] + h.y * Wrep[(f0 + 1) * 3 + 2];
    #pragma unroll
    for (int d = 1; d < 64; d <<= 1) {
        nrm += __shfl_xor(nrm, d);
        p0 += __shfl_xor(p0, d);
        p1 += __shfl_xor(p1, d);
        p2 += __shfl_xor(p2, d);
    }
    if (lane == 0) {
        float inv = 1.f / fmaxf(sqrtf(nrm), L2_EPS);
        out[node * 3 + 0] = p0 * inv + brep[0];
        out[node * 3 + 1] = p1 * inv + brep[1];
        out[node * 3 + 2] = p2 * inv + brep[2];
    }
}

// ---------------- host ----------------

extern "C" void kernel_launch(void* const* d_in, const int* in_sizes, int n_in,
                              void* d_out, int out_size, void* d_ws, size_t ws_size,
                              hipStream_t stream) {
    const int N = in_sizes[0] / 3;   // 100000
    const int E = in_sizes[1] / 2;   // 1600000

    const float* x    = (const float*)d_in[0];
    const int*   ei   = (const int*)d_in[1];   // int32 (JAX default x64-disabled)
    const int* esrc = ei;
    const int* edst = ei + E;
    const float* W1 = (const float*)d_in[2];  const float* b1 = (const float*)d_in[3];
    const float* W2 = (const float*)d_in[4];  const float* b2 = (const float*)d_in[5];
    const float* W3 = (const float*)d_in[6];  const float* b3 = (const float*)d_in[7];
    const float* W4 = (const float*)d_in[8];  const float* b4 = (const float*)d_in[9];
    const float* g1 = (const float*)d_in[10]; const float* be1 = (const float*)d_in[11];
    const float* g2 = (const float*)d_in[12]; const float* be2 = (const float*)d_in[13];
    const float* g3 = (const float*)d_in[14]; const float* be3 = (const float*)d_in[15];
    const float* Wrep = (const float*)d_in[16]; const float* brep = (const float*)d_in[17];
    float* out = (float*)d_out;

    char* w = (char*)d_ws;
    size_t off = 0;
    auto alloc = [&](size_t bytes) { size_t o = off; off = (off + bytes + 255) & ~(size_t)255; return o; };
    int*   cnt    = (int*)(w + alloc((size_t)N * 4));
    int*   rowptr = (int*)(w + alloc((size_t)(N + 1) * 4));
    int*   cursor = (int*)(w + alloc((size_t)N * 4));
    float* dinv   = (float*)(w + alloc((size_t)N * 4));
    int*   srcS   = (int*)(w + alloc((size_t)E * 4));
    float* normS  = (float*)(w + alloc((size_t)E * 4));
    short* Wp     = (short*)(w + alloc(32768 * 2));
    float* S      = (float*)(w + alloc(256 * 4));
    float* AC     = (float*)(w + alloc(256 * 4));
    float* t1     = (float*)(w + alloc((size_t)N * 3 * 4));
    float* t2     = (float*)(w + alloc((size_t)N * 3 * 4));
    float* t3     = (float*)(w + alloc((size_t)N * 3 * 4));
    float* A      = (float*)(w + alloc((size_t)N * 128 * 4));
    float* B      = (float*)(w + alloc((size_t)N * 128 * 4));
    float* C      = (float*)(w + alloc((size_t)N * 128 * 4));
    float* OUT    = (float*)(w + alloc((size_t)N * 128 * 4));
    // total ~224 MB

    int gE = (E + 255) / 256;
    int gN = (N + 255) / 256;
    int gW = (N + 3) / 4;       // wave-per-node kernels
    int gM = (N + 63) / 64;     // MFMA gemm blocks

    // --- preprocessing ---
    hipMemsetAsync(cnt, 0, (size_t)N * 4, stream);
    k_hist<<<gE, 256, 0, stream>>>(edst, cnt, E);
    k_dinv<<<gN, 256, 0, stream>>>(cnt, dinv, N);
    k_scan<<<1, 1024, 0, stream>>>(cnt, rowptr, cursor, N);
    k_fill<<<gE, 256, 0, stream>>>(esrc, edst, dinv, cursor, srcS, normS, E);

    // --- layer 1 (F_in=3) ---
    k_prop3<<<gN, 256, 0, stream>>>(x, nullptr, t1, rowptr, srcS, normS, 1.f, 0.f, N);
    k_prop3<<<gN, 256, 0, stream>>>(t1, x, t2, rowptr, srcS, normS, 2.f, -1.f, N);
    k_prop3<<<gN, 256, 0, stream>>>(t2, t1, t3, rowptr, srcS, normS, 2.f, -1.f, N);
    k_gemm1<<<(N + 1) / 2, 256, 0, stream>>>(x, t1, t2, t3, W1, b1, OUT, N);
    hipMemsetAsync(S, 0, 256 * 4, stream);
    k_stats<<<(N + 511) / 512, 256, 0, stream>>>(OUT, S, N, 0);
    k_bnfin<<<1, 128, 0, stream>>>(S, g1, be1, AC, N);
    k_bnapply<<<(N * 32 + 255) / 256, 256, 0, stream>>>(OUT, AC, A, N * 32, 0);

    // --- layers 2..4 ---
    const float* Ws[3]  = {W2, W3, W4};
    const float* bs[3]  = {b2, b3, b4};
    const float* gs[3]  = {g2, g3, nullptr};
    const float* bes[3] = {be2, be3, nullptr};
    int acts[3] = {0, 1, 2};  // leaky, relu, none

    for (int l = 0; l < 3; ++l) {
        const float* Wl = Ws[l];
        // T1 = L A
        k_prop128<<<gW, 256, 0, stream>>>(A, nullptr, B, rowptr, srcS, normS, 1.f, 0.f, N);
        // OUT = [T0|T1] @ [W0;W1] + b
        k_packW<<<128, 256, 0, stream>>>(Wl, Wl + 16384, Wp);
        k_gemm<<<gM, 256, 0, stream>>>(A, B, Wp, bs[l], OUT, N, 1, 0);
        // T2 = 2 L T1 - T0
        k_prop128<<<gW, 256, 0, stream>>>(B, A, C, rowptr, srcS, normS, 2.f, -1.f, N);
        // T3 = 2 L T2 - T1  (overwrites A/T0, no longer needed)
        k_prop128<<<gW, 256, 0, stream>>>(C, B, A, rowptr, srcS, normS, 2.f, -1.f, N);
        // OUT += [T2|T3] @ [W2;W3]
        k_packW<<<128, 256, 0, stream>>>(Wl + 2 * 16384, Wl + 3 * 16384, Wp);
        k_gemm<<<gM, 256, 0, stream>>>(C, A, Wp, nullptr, OUT, N, 0, 1);

        if (l < 2) {
            hipMemsetAsync(S, 0, 256 * 4, stream);
            k_stats<<<(N + 511) / 512, 256, 0, stream>>>(OUT, S, N, acts[l]);
            k_bnfin<<<1, 128, 0, stream>>>(S, gs[l], bes[l], AC, N);
            k_bnapply<<<(N * 32 + 255) / 256, 256, 0, stream>>>(OUT, AC, A, N * 32, acts[l]);
        }
    }

    // --- final: L2 norm + projection ---
    k_final<<<gW, 256, 0, stream>>>(OUT, Wrep, brep, out, N);
}

// Round 2
// 1644.628 us; speedup vs baseline: 1.4071x; 1.4071x over previous
//
#include <hip/hip_runtime.h>
#include <hip/hip_bf16.h>

// ChebConv GNN, N=100000, E=1600000, HID=128, K=4.
// R2: feature matrices stored bf16 (halves gather traffic; MFMA A-fragments load
//     directly as short8), single K=512 GEMM per layer (two-stage LDS weight reload).

#define HID 128
#define NEG 0.01f
#define BN_EPS 1e-5f
#define L2_EPS 1e-12f

typedef __attribute__((ext_vector_type(8))) short short8;
typedef __attribute__((ext_vector_type(4))) float floatx4;

__device__ __forceinline__ short f2bf(float f) {
    unsigned u = __float_as_uint(f);
    return (short)((u + 0x7fffu + ((u >> 16) & 1u)) >> 16);
}
__device__ __forceinline__ unsigned pack2bf(float x, float y) {
    return (unsigned)(unsigned short)f2bf(x) | ((unsigned)(unsigned short)f2bf(y) << 16);
}
__device__ __forceinline__ float bflo(unsigned u) { return __uint_as_float(u << 16); }
__device__ __forceinline__ float bfhi(unsigned u) { return __uint_as_float(u & 0xffff0000u); }

__device__ __forceinline__ float actf(float v, int act) {
    if (act == 0) return v >= 0.f ? v : NEG * v;   // leaky_relu
    if (act == 1) return v > 0.f ? v : 0.f;        // relu
    return v;
}

// ---------------- preprocessing ----------------

__global__ __launch_bounds__(256) void k_hist(const int* __restrict__ dst, int* __restrict__ cnt, int E) {
    int e = blockIdx.x * 256 + threadIdx.x;
    if (e < E) atomicAdd(&cnt[dst[e]], 1);
}

__global__ __launch_bounds__(256) void k_dinv(const int* __restrict__ cnt, float* __restrict__ dinv, int N) {
    int i = blockIdx.x * 256 + threadIdx.x;
    if (i < N) {
        int d = cnt[i];
        dinv[i] = d > 0 ? rsqrtf((float)d) : 0.f;
    }
}

__global__ __launch_bounds__(1024) void k_scan(const int* __restrict__ cnt, int* __restrict__ rowptr,
                                               int* __restrict__ cursor, int n) {
    __shared__ int wsum[17];
    __shared__ int carry_s;
    int tid = threadIdx.x;
    int lane = tid & 63, w = tid >> 6;
    if (tid == 0) carry_s = 0;
    __syncthreads();
    for (int base = 0; base < n; base += 1024) {
        int i = base + tid;
        int v = (i < n) ? cnt[i] : 0;
        int s = v;
        #pragma unroll
        for (int d = 1; d < 64; d <<= 1) {
            int t = __shfl_up(s, d);
            if (lane >= d) s += t;
        }
        if (lane == 63) wsum[w] = s;
        __syncthreads();
        if (w == 0 && lane < 16) {
            int x = wsum[lane];
            int s2 = x;
            #pragma unroll
            for (int d = 1; d < 16; d <<= 1) {
                int t = __shfl_up(s2, d);
                if (lane >= d) s2 += t;
            }
            wsum[lane] = s2 - x;
            if (lane == 15) wsum[16] = s2;
        }
        __syncthreads();
        int excl = carry_s + wsum[w] + (s - v);
        if (i < n) { rowptr[i] = excl; cursor[i] = excl; }
        __syncthreads();
        if (tid == 0) carry_s += wsum[16];
    }
    if (tid == 0) rowptr[n] = carry_s;
}

__global__ __launch_bounds__(256) void k_fill(const int* __restrict__ src, const int* __restrict__ dst,
                                              const float* __restrict__ dinv, int* __restrict__ cursor,
                                              int* __restrict__ srcS, float* __restrict__ normS, int E) {
    int e = blockIdx.x * 256 + threadIdx.x;
    if (e >= E) return;
    int s = src[e], d = dst[e];
    int pos = atomicAdd(&cursor[d], 1);
    srcS[pos] = s;
    normS[pos] = -(dinv[s] * dinv[d]);
}

// ---------------- propagation ----------------

// F=3 fp32, one thread per node. out = a*prop(T) + b*prev
__global__ __launch_bounds__(256) void k_prop3(const float* __restrict__ T, const float* __restrict__ prev,
                                               float* __restrict__ out, const int* __restrict__ rowptr,
                                               const int* __restrict__ srcS, const float* __restrict__ normS,
                                               float a, float b, int N) {
    int i = blockIdx.x * 256 + threadIdx.x;
    if (i >= N) return;
    float a0 = 0.f, a1 = 0.f, a2 = 0.f;
    int e1 = rowptr[i + 1];
    for (int e = rowptr[i]; e < e1; ++e) {
        int s = srcS[e];
        float w = normS[e];
        a0 += w * T[s * 3 + 0];
        a1 += w * T[s * 3 + 1];
        a2 += w * T[s * 3 + 2];
    }
    float r0 = a * a0, r1 = a * a1, r2 = a * a2;
    if (prev) {
        r0 += b * prev[i * 3 + 0];
        r1 += b * prev[i * 3 + 1];
        r2 += b * prev[i * 3 + 2];
    }
    out[i * 3 + 0] = r0;
    out[i * 3 + 1] = r1;
    out[i * 3 + 2] = r2;
}

// F=128 bf16 in/out, fp32 accumulate. One wave per node, 1 uint (2 feats) per lane.
__global__ __launch_bounds__(256) void k_prop128(const unsigned* __restrict__ T, const unsigned* __restrict__ prev,
                                                 unsigned* __restrict__ out, const int* __restrict__ rowptr,
                                                 const int* __restrict__ srcS, const float* __restrict__ normS,
                                                 float a, float b, int N) {
    int node = blockIdx.x * 4 + (threadIdx.x >> 6);
    if (node >= N) return;
    node = __builtin_amdgcn_readfirstlane(node);  // wave-uniform -> scalar edge metadata loads
    int lane = threadIdx.x & 63;
    int e0 = rowptr[node], e1 = rowptr[node + 1];
    float accx = 0.f, accy = 0.f;
    int e = e0;
    for (; e + 1 < e1; e += 2) {
        int s0 = srcS[e], s1 = srcS[e + 1];
        float w0 = normS[e], w1 = normS[e + 1];
        unsigned t0 = T[(size_t)s0 * 64 + lane];
        unsigned t1 = T[(size_t)s1 * 64 + lane];
        accx += w0 * bflo(t0); accy += w0 * bfhi(t0);
        accx += w1 * bflo(t1); accy += w1 * bfhi(t1);
    }
    if (e < e1) {
        int s0 = srcS[e];
        float w0 = normS[e];
        unsigned t0 = T[(size_t)s0 * 64 + lane];
        accx += w0 * bflo(t0); accy += w0 * bfhi(t0);
    }
    float rx = a * accx, ry = a * accy;
    if (prev) {
        unsigned p = prev[(size_t)node * 64 + lane];
        rx += b * bflo(p);
        ry += b * bfhi(p);
    }
    out[(size_t)node * 64 + lane] = pack2bf(rx, ry);
}

// ---------------- layer-1 dense (K=12 tiny GEMM), fp32 out ----------------

__global__ __launch_bounds__(256) void k_gemm1(const float* __restrict__ x, const float* __restrict__ t1,
                                               const float* __restrict__ t2, const float* __restrict__ t3,
                                               const float* __restrict__ W, const float* __restrict__ b,
                                               float* __restrict__ OUT, int N) {
    __shared__ float Wl[12 * 128];
    __shared__ float bl[128];
    int tid = threadIdx.x;
    for (int i = tid; i < 1536; i += 256) Wl[i] = W[i];
    if (tid < 128) bl[tid] = b[tid];
    __syncthreads();
    int node = blockIdx.x * 2 + (tid >> 7);
    if (node >= N) return;
    int f = tid & 127;
    float acc = bl[f];
    const float* rows[4] = {x, t1, t2, t3};
    #pragma unroll
    for (int k = 0; k < 4; ++k) {
        const float* r = rows[k] + (size_t)node * 3;
        acc += r[0] * Wl[(k * 3 + 0) * 128 + f];
        acc += r[1] * Wl[(k * 3 + 1) * 128 + f];
        acc += r[2] * Wl[(k * 3 + 2) * 128 + f];
    }
    OUT[(size_t)node * 128 + f] = acc;
}

// ---------------- big GEMM: OUT[M,128] = [T0|T1|T2|T3][M,512] @ Wp[512,128] + b ----------------

// pack all 4 W_k (each 128x128 fp32, contiguous [K,fin,fout]) into bf16 B-fragment order:
// flat = ((ks*8+nt)*64+lane)*8+j -> B[kk = ks*32 + (lane>>4)*8 + j][c = nt*16 + (lane&15)], kk in [0,512)
__global__ __launch_bounds__(256) void k_packW(const float* __restrict__ W, short* __restrict__ Wp) {
    int idx = blockIdx.x * 256 + threadIdx.x;  // 0..65535
    int j = idx & 7;
    int lane = (idx >> 3) & 63;
    int rest = idx >> 9;
    int nt = rest & 7;
    int ks = rest >> 3;                         // 0..15
    int kk = ks * 32 + (lane >> 4) * 8 + j;     // 0..511
    int c = nt * 16 + (lane & 15);
    Wp[idx] = f2bf(W[(size_t)(kk >> 7) * 16384 + (kk & 127) * 128 + c]);
}

__global__ __launch_bounds__(256) void k_gemm512(const short* __restrict__ T0, const short* __restrict__ T1,
                                                 const short* __restrict__ T2, const short* __restrict__ T3,
                                                 const short* __restrict__ Wp, const float* __restrict__ bias,
                                                 float* __restrict__ OUT, int M) {
    __shared__ short Wlds[32768];  // 64 KB: half of the [512,128] bf16 weight, fragment order
    int tid = threadIdx.x;
    int lane = tid & 63, wave = tid >> 6;
    int r0 = blockIdx.x * 64 + wave * 16;
    int row = r0 + (lane & 15);
    int quad = lane >> 4;
    int rowc = row < M ? row : M - 1;
    size_t rb = (size_t)rowc * 128;
    const short* Ts[4] = {T0, T1, T2, T3};
    floatx4 acc[8];
    #pragma unroll
    for (int i = 0; i < 8; ++i) { acc[i][0] = 0.f; acc[i][1] = 0.f; acc[i][2] = 0.f; acc[i][3] = 0.f; }
    #pragma unroll
    for (int stage = 0; stage < 2; ++stage) {
        if (stage) __syncthreads();
        for (int i = tid; i < 4096; i += 256) ((int4*)Wlds)[i] = ((const int4*)Wp)[stage * 4096 + i];
        __syncthreads();
        #pragma unroll
        for (int ksl = 0; ksl < 8; ++ksl) {
            const short* Tm = Ts[stage * 2 + (ksl >> 2)];
            short8 af = *((const short8*)(Tm + rb + (ksl & 3) * 32 + quad * 8));
            #pragma unroll
            for (int nt = 0; nt < 8; ++nt) {
                short8 bf = *((const short8*)(Wlds + ((ksl * 8 + nt) * 64 + lane) * 8));
                acc[nt] = __builtin_amdgcn_mfma_f32_16x16x32_bf16(af, bf, acc[nt], 0, 0, 0);
            }
        }
    }
    // C/D layout: col = lane&15, row = quad*4 + reg
    int col0 = lane & 15;
    int rbase = r0 + quad * 4;
    #pragma unroll
    for (int nt = 0; nt < 8; ++nt) {
        int c = nt * 16 + col0;
        float bv = bias[c];
        #pragma unroll
        for (int rg = 0; rg < 4; ++rg) {
            int r = rbase + rg;
            if (r < M) OUT[(size_t)r * 128 + c] = acc[nt][rg] + bv;
        }
    }
}

// ---------------- BatchNorm ----------------

__global__ __launch_bounds__(256) void k_stats(const float* __restrict__ X, float* __restrict__ S, int N, int act) {
    int col = threadIdx.x & 127, rh = threadIdx.x >> 7;
    int r0 = blockIdx.x * 512;
    int rend = r0 + 512 < N ? r0 + 512 : N;
    float s1 = 0.f, s2 = 0.f;
    for (int r = r0 + rh; r < rend; r += 2) {
        float v = actf(X[(size_t)r * 128 + col], act);
        s1 += v;
        s2 += v * v;
    }
    atomicAdd(&S[col], s1);
    atomicAdd(&S[col + 128], s2);
}

__global__ __launch_bounds__(128) void k_bnfin(const float* __restrict__ S, const float* __restrict__ g,
                                               const float* __restrict__ be, float* __restrict__ AC, int N) {
    int f = threadIdx.x;
    float mu = S[f] / (float)N;
    float var = S[f + 128] / (float)N - mu * mu;
    float rstd = rsqrtf(var + BN_EPS);
    float a = g[f] * rstd;
    AC[f] = a;
    AC[f + 128] = be[f] - mu * a;
}

// read fp32 X, apply act + BN affine, write bf16 (packed pairs)
__global__ __launch_bounds__(256) void k_bnapply(const float* __restrict__ X, const float* __restrict__ AC,
                                                 unsigned* __restrict__ Y, int n4, int act) {
    int i = blockIdx.x * 256 + threadIdx.x;
    if (i >= n4) return;
    float4 v = ((const float4*)X)[i];
    int col = (i * 4) & 127;
    float4 a = *((const float4*)(AC + col));
    float4 c = *((const float4*)(AC + 128 + col));
    v.x = actf(v.x, act) * a.x + c.x;
    v.y = actf(v.y, act) * a.y + c.y;
    v.z = actf(v.z, act) * a.z + c.z;
    v.w = actf(v.w, act) * a.w + c.w;
    uint2 o;
    o.x = pack2bf(v.x, v.y);
    o.y = pack2bf(v.z, v.w);
    ((uint2*)Y)[i] = o;
}

// ---------------- final: L2-normalize rows + project 128->3 ----------------

__global__ __launch_bounds__(256) void k_final(const float* __restrict__ H, const float* __restrict__ Wrep,
                                               const float* __restrict__ brep, float* __restrict__ out, int N) {
    int node = blockIdx.x * 4 + (threadIdx.x >> 6);
    if (node >= N) return;
    int lane = threadIdx.x & 63;
    float2 h = ((const float2*)H)[(size_t)node * 64 + lane];
    int f0 = 2 * lane;
    float nrm = h.x * h.x + h.y * h.y;
    float p0 = h.x * Wrep[f0 * 3 + 0] + h.y * Wrep[(f0 + 1) * 3 + 0];
    float p1 = h.x * Wrep[f0 * 3 + 1] + h.y * Wrep[(f0 + 1) * 3 + 1];
    float p2 = h.x * Wrep[f0 * 3 + 2] + h.y * Wrep[(f0 + 1) * 3 + 2];
    #pragma unroll
    for (int d = 1; d < 64; d <<= 1) {
        nrm += __shfl_xor(nrm, d);
        p0 += __shfl_xor(p0, d);
        p1 += __shfl_xor(p1, d);
        p2 += __shfl_xor(p2, d);
    }
    if (lane == 0) {
        float inv = 1.f / fmaxf(sqrtf(nrm), L2_EPS);
        out[node * 3 + 0] = p0 * inv + brep[0];
        out[node * 3 + 1] = p1 * inv + brep[1];
        out[node * 3 + 2] = p2 * inv + brep[2];
    }
}

// ---------------- host ----------------

extern "C" void kernel_launch(void* const* d_in, const int* in_sizes, int n_in,
                              void* d_out, int out_size, void* d_ws, size_t ws_size,
                              hipStream_t stream) {
    const int N = in_sizes[0] / 3;   // 100000
    const int E = in_sizes[1] / 2;   // 1600000

    const float* x    = (const float*)d_in[0];
    const int*   ei   = (const int*)d_in[1];
    const int* esrc = ei;
    const int* edst = ei + E;
    const float* W1 = (const float*)d_in[2];  const float* b1 = (const float*)d_in[3];
    const float* W2 = (const float*)d_in[4];  const float* b2 = (const float*)d_in[5];
    const float* W3 = (const float*)d_in[6];  const float* b3 = (const float*)d_in[7];
    const float* W4 = (const float*)d_in[8];  const float* b4 = (const float*)d_in[9];
    const float* g1 = (const float*)d_in[10]; const float* be1 = (const float*)d_in[11];
    const float* g2 = (const float*)d_in[12]; const float* be2 = (const float*)d_in[13];
    const float* g3 = (const float*)d_in[14]; const float* be3 = (const float*)d_in[15];
    const float* Wrep = (const float*)d_in[16]; const float* brep = (const float*)d_in[17];
    float* out = (float*)d_out;

    char* w = (char*)d_ws;
    size_t off = 0;
    auto alloc = [&](size_t bytes) { size_t o = off; off = (off + bytes + 255) & ~(size_t)255; return o; };
    int*   cnt    = (int*)(w + alloc((size_t)N * 4));
    int*   rowptr = (int*)(w + alloc((size_t)(N + 1) * 4));
    int*   cursor = (int*)(w + alloc((size_t)N * 4));
    float* dinv   = (float*)(w + alloc((size_t)N * 4));
    int*   srcS   = (int*)(w + alloc((size_t)E * 4));
    float* normS  = (float*)(w + alloc((size_t)E * 4));
    short* Wp     = (short*)(w + alloc(65536 * 2));
    float* S      = (float*)(w + alloc(256 * 4));
    float* AC     = (float*)(w + alloc(256 * 4));
    float* t1f    = (float*)(w + alloc((size_t)N * 3 * 4));
    float* t2f    = (float*)(w + alloc((size_t)N * 3 * 4));
    float* t3f    = (float*)(w + alloc((size_t)N * 3 * 4));
    short* T0     = (short*)(w + alloc((size_t)N * 128 * 2));  // bf16 feature bufs
    short* T1     = (short*)(w + alloc((size_t)N * 128 * 2));
    short* T2     = (short*)(w + alloc((size_t)N * 128 * 2));
    short* T3     = (short*)(w + alloc((size_t)N * 128 * 2));
    float* OUT    = (float*)(w + alloc((size_t)N * 128 * 4));
    // total ~180 MB

    int gE = (E + 255) / 256;
    int gN = (N + 255) / 256;
    int gW = (N + 3) / 4;       // wave-per-node kernels
    int gM = (N + 63) / 64;     // MFMA gemm blocks

    // --- preprocessing ---
    hipMemsetAsync(cnt, 0, (size_t)N * 4, stream);
    k_hist<<<gE, 256, 0, stream>>>(edst, cnt, E);
    k_dinv<<<gN, 256, 0, stream>>>(cnt, dinv, N);
    k_scan<<<1, 1024, 0, stream>>>(cnt, rowptr, cursor, N);
    k_fill<<<gE, 256, 0, stream>>>(esrc, edst, dinv, cursor, srcS, normS, E);

    // --- layer 1 (F_in=3, fp32) ---
    k_prop3<<<gN, 256, 0, stream>>>(x, nullptr, t1f, rowptr, srcS, normS, 1.f, 0.f, N);
    k_prop3<<<gN, 256, 0, stream>>>(t1f, x, t2f, rowptr, srcS, normS, 2.f, -1.f, N);
    k_prop3<<<gN, 256, 0, stream>>>(t2f, t1f, t3f, rowptr, srcS, normS, 2.f, -1.f, N);
    k_gemm1<<<(N + 1) / 2, 256, 0, stream>>>(x, t1f, t2f, t3f, W1, b1, OUT, N);
    hipMemsetAsync(S, 0, 256 * 4, stream);
    k_stats<<<(N + 511) / 512, 256, 0, stream>>>(OUT, S, N, 0);
    k_bnfin<<<1, 128, 0, stream>>>(S, g1, be1, AC, N);
    k_bnapply<<<(N * 32 + 255) / 256, 256, 0, stream>>>(OUT, AC, (unsigned*)T0, N * 32, 0);

    // --- layers 2..4 ---
    const float* Ws[3]  = {W2, W3, W4};
    const float* bs[3]  = {b2, b3, b4};
    const float* gs[3]  = {g2, g3, nullptr};
    const float* bes[3] = {be2, be3, nullptr};
    int acts[3] = {0, 1, 2};  // leaky, relu, none

    for (int l = 0; l < 3; ++l) {
        const unsigned* U0 = (const unsigned*)T0;
        unsigned* U1 = (unsigned*)T1;
        unsigned* U2 = (unsigned*)T2;
        unsigned* U3 = (unsigned*)T3;
        k_prop128<<<gW, 256, 0, stream>>>(U0, nullptr, U1, rowptr, srcS, normS, 1.f, 0.f, N);
        k_prop128<<<gW, 256, 0, stream>>>((const unsigned*)U1, U0, U2, rowptr, srcS, normS, 2.f, -1.f, N);
        k_prop128<<<gW, 256, 0, stream>>>((const unsigned*)U2, (const unsigned*)U1, U3, rowptr, srcS, normS, 2.f, -1.f, N);
        k_packW<<<256, 256, 0, stream>>>(Ws[l], Wp);
        k_gemm512<<<gM, 256, 0, stream>>>(T0, T1, T2, T3, Wp, bs[l], OUT, N);

        if (l < 2) {
            hipMemsetAsync(S, 0, 256 * 4, stream);
            k_stats<<<(N + 511) / 512, 256, 0, stream>>>(OUT, S, N, acts[l]);
            k_bnfin<<<1, 128, 0, stream>>>(S, gs[l], bes[l], AC, N);
            k_bnapply<<<(N * 32 + 255) / 256, 256, 0, stream>>>(OUT, AC, (unsigned*)T0, N * 32, acts[l]);
        }
    }

    // --- final: L2 norm + projection ---
    k_final<<<gW, 256, 0, stream>>>(OUT, Wrep, brep, out, N);
}

// Round 3
// 1536.299 us; speedup vs baseline: 1.5064x; 1.0705x over previous
//
#include <hip/hip_runtime.h>
#include <hip/hip_bf16.h>

// ChebConv GNN, N=100000, E=1600000, HID=128, K=4.
// R3: interleaved (src,norm) int2 edge records (halves fill scatter lines),
//     8-deep gather batching in prop128 for memory-level parallelism.

#define HID 128
#define NEG 0.01f
#define BN_EPS 1e-5f
#define L2_EPS 1e-12f

typedef __attribute__((ext_vector_type(8))) short short8;
typedef __attribute__((ext_vector_type(4))) float floatx4;

__device__ __forceinline__ short f2bf(float f) {
    unsigned u = __float_as_uint(f);
    return (short)((u + 0x7fffu + ((u >> 16) & 1u)) >> 16);
}
__device__ __forceinline__ unsigned pack2bf(float x, float y) {
    return (unsigned)(unsigned short)f2bf(x) | ((unsigned)(unsigned short)f2bf(y) << 16);
}
__device__ __forceinline__ float bflo(unsigned u) { return __uint_as_float(u << 16); }
__device__ __forceinline__ float bfhi(unsigned u) { return __uint_as_float(u & 0xffff0000u); }

__device__ __forceinline__ float actf(float v, int act) {
    if (act == 0) return v >= 0.f ? v : NEG * v;   // leaky_relu
    if (act == 1) return v > 0.f ? v : 0.f;        // relu
    return v;
}

// ---------------- preprocessing ----------------

__global__ __launch_bounds__(256) void k_hist(const int* __restrict__ dst, int* __restrict__ cnt, int E) {
    int e = blockIdx.x * 256 + threadIdx.x;
    if (e < E) atomicAdd(&cnt[dst[e]], 1);
}

__global__ __launch_bounds__(256) void k_dinv(const int* __restrict__ cnt, float* __restrict__ dinv, int N) {
    int i = blockIdx.x * 256 + threadIdx.x;
    if (i < N) {
        int d = cnt[i];
        dinv[i] = d > 0 ? rsqrtf((float)d) : 0.f;
    }
}

__global__ __launch_bounds__(1024) void k_scan(const int* __restrict__ cnt, int* __restrict__ rowptr,
                                               int* __restrict__ cursor, int n) {
    __shared__ int wsum[17];
    __shared__ int carry_s;
    int tid = threadIdx.x;
    int lane = tid & 63, w = tid >> 6;
    if (tid == 0) carry_s = 0;
    __syncthreads();
    for (int base = 0; base < n; base += 1024) {
        int i = base + tid;
        int v = (i < n) ? cnt[i] : 0;
        int s = v;
        #pragma unroll
        for (int d = 1; d < 64; d <<= 1) {
            int t = __shfl_up(s, d);
            if (lane >= d) s += t;
        }
        if (lane == 63) wsum[w] = s;
        __syncthreads();
        if (w == 0 && lane < 16) {
            int x = wsum[lane];
            int s2 = x;
            #pragma unroll
            for (int d = 1; d < 16; d <<= 1) {
                int t = __shfl_up(s2, d);
                if (lane >= d) s2 += t;
            }
            wsum[lane] = s2 - x;
            if (lane == 15) wsum[16] = s2;
        }
        __syncthreads();
        int excl = carry_s + wsum[w] + (s - v);
        if (i < n) { rowptr[i] = excl; cursor[i] = excl; }
        __syncthreads();
        if (tid == 0) carry_s += wsum[16];
    }
    if (tid == 0) rowptr[n] = carry_s;
}

// one interleaved int2 record per edge: {src, norm(as int)}
__global__ __launch_bounds__(256) void k_fill(const int* __restrict__ src, const int* __restrict__ dst,
                                              const float* __restrict__ dinv, int* __restrict__ cursor,
                                              int2* __restrict__ edges, int E) {
    int e = blockIdx.x * 256 + threadIdx.x;
    if (e >= E) return;
    int s = src[e], d = dst[e];
    int pos = atomicAdd(&cursor[d], 1);
    int2 rec;
    rec.x = s;
    rec.y = __float_as_int(-(dinv[s] * dinv[d]));
    edges[pos] = rec;
}

// ---------------- propagation ----------------

// F=3 fp32, one thread per node. out = a*prop(T) + b*prev
__global__ __launch_bounds__(256) void k_prop3(const float* __restrict__ T, const float* __restrict__ prev,
                                               float* __restrict__ out, const int* __restrict__ rowptr,
                                               const int2* __restrict__ edges,
                                               float a, float b, int N) {
    int i = blockIdx.x * 256 + threadIdx.x;
    if (i >= N) return;
    float a0 = 0.f, a1 = 0.f, a2 = 0.f;
    int e1 = rowptr[i + 1];
    for (int e = rowptr[i]; e < e1; ++e) {
        int2 r = edges[e];
        float w = __int_as_float(r.y);
        a0 += w * T[r.x * 3 + 0];
        a1 += w * T[r.x * 3 + 1];
        a2 += w * T[r.x * 3 + 2];
    }
    float r0 = a * a0, r1 = a * a1, r2 = a * a2;
    if (prev) {
        r0 += b * prev[i * 3 + 0];
        r1 += b * prev[i * 3 + 1];
        r2 += b * prev[i * 3 + 2];
    }
    out[i * 3 + 0] = r0;
    out[i * 3 + 1] = r1;
    out[i * 3 + 2] = r2;
}

// F=128 bf16 in/out, fp32 accumulate. One wave per node, 8-deep gather batching.
__global__ __launch_bounds__(256) void k_prop128(const unsigned* __restrict__ T, const unsigned* __restrict__ prev,
                                                 unsigned* __restrict__ out, const int* __restrict__ rowptr,
                                                 const int2* __restrict__ edges,
                                                 float a, float b, int N) {
    int node = blockIdx.x * 4 + (threadIdx.x >> 6);
    if (node >= N) return;
    node = __builtin_amdgcn_readfirstlane(node);  // wave-uniform -> scalar loads for edge metadata
    int lane = threadIdx.x & 63;
    int e0 = rowptr[node], e1 = rowptr[node + 1];
    float accx = 0.f, accy = 0.f;
    int e = e0;
    // 8-deep batches: 8 gathers in flight per wave
    for (; e + 8 <= e1; e += 8) {
        int2 rec[8];
        unsigned t[8];
        #pragma unroll
        for (int j = 0; j < 8; ++j) rec[j] = edges[e + j];
        #pragma unroll
        for (int j = 0; j < 8; ++j) t[j] = T[(size_t)rec[j].x * 64 + lane];
        #pragma unroll
        for (int j = 0; j < 8; ++j) {
            float w = __int_as_float(rec[j].y);
            accx += w * bflo(t[j]);
            accy += w * bfhi(t[j]);
        }
    }
    // tail
    for (; e < e1; ++e) {
        int2 r = edges[e];
        float w = __int_as_float(r.y);
        unsigned t0 = T[(size_t)r.x * 64 + lane];
        accx += w * bflo(t0);
        accy += w * bfhi(t0);
    }
    float rx = a * accx, ry = a * accy;
    if (prev) {
        unsigned p = prev[(size_t)node * 64 + lane];
        rx += b * bflo(p);
        ry += b * bfhi(p);
    }
    out[(size_t)node * 64 + lane] = pack2bf(rx, ry);
}

// ---------------- layer-1 dense (K=12 tiny GEMM), fp32 out ----------------

__global__ __launch_bounds__(256) void k_gemm1(const float* __restrict__ x, const float* __restrict__ t1,
                                               const float* __restrict__ t2, const float* __restrict__ t3,
                                               const float* __restrict__ W, const float* __restrict__ b,
                                               float* __restrict__ OUT, int N) {
    __shared__ float Wl[12 * 128];
    __shared__ float bl[128];
    int tid = threadIdx.x;
    for (int i = tid; i < 1536; i += 256) Wl[i] = W[i];
    if (tid < 128) bl[tid] = b[tid];
    __syncthreads();
    int node = blockIdx.x * 2 + (tid >> 7);
    if (node >= N) return;
    int f = tid & 127;
    float acc = bl[f];
    const float* rows[4] = {x, t1, t2, t3};
    #pragma unroll
    for (int k = 0; k < 4; ++k) {
        const float* r = rows[k] + (size_t)node * 3;
        acc += r[0] * Wl[(k * 3 + 0) * 128 + f];
        acc += r[1] * Wl[(k * 3 + 1) * 128 + f];
        acc += r[2] * Wl[(k * 3 + 2) * 128 + f];
    }
    OUT[(size_t)node * 128 + f] = acc;
}

// ---------------- big GEMM: OUT[M,128] = [T0|T1|T2|T3][M,512] @ Wp[512,128] + b ----------------

// pack all 3 layers' W (each [4,128,128] fp32) into bf16 B-fragment order.
// layer L flat idx = ((ks*8+nt)*64+lane)*8+j -> B[kk = ks*32+(lane>>4)*8+j][c = nt*16+(lane&15)]
__global__ __launch_bounds__(256) void k_packW(const float* __restrict__ WA, const float* __restrict__ WB,
                                               const float* __restrict__ WC, short* __restrict__ Wp) {
    int gid = blockIdx.x * 256 + threadIdx.x;  // 0..196607
    int L = gid >> 16;
    int idx = gid & 65535;
    int j = idx & 7;
    int lane = (idx >> 3) & 63;
    int rest = idx >> 9;
    int nt = rest & 7;
    int ks = rest >> 3;
    int kk = ks * 32 + (lane >> 4) * 8 + j;
    int c = nt * 16 + (lane & 15);
    const float* W = (L == 0) ? WA : (L == 1) ? WB : WC;
    Wp[gid] = f2bf(W[(size_t)(kk >> 7) * 16384 + (kk & 127) * 128 + c]);
}

__global__ __launch_bounds__(256) void k_gemm512(const short* __restrict__ T0, const short* __restrict__ T1,
                                                 const short* __restrict__ T2, const short* __restrict__ T3,
                                                 const short* __restrict__ Wp, const float* __restrict__ bias,
                                                 float* __restrict__ OUT, int M) {
    __shared__ short Wlds[32768];  // 64 KB: half of the [512,128] bf16 weight, fragment order
    int tid = threadIdx.x;
    int lane = tid & 63, wave = tid >> 6;
    int r0 = blockIdx.x * 64 + wave * 16;
    int row = r0 + (lane & 15);
    int quad = lane >> 4;
    int rowc = row < M ? row : M - 1;
    size_t rb = (size_t)rowc * 128;
    const short* Ts[4] = {T0, T1, T2, T3};
    floatx4 acc[8];
    #pragma unroll
    for (int i = 0; i < 8; ++i) { acc[i][0] = 0.f; acc[i][1] = 0.f; acc[i][2] = 0.f; acc[i][3] = 0.f; }
    #pragma unroll
    for (int stage = 0; stage < 2; ++stage) {
        if (stage) __syncthreads();
        for (int i = tid; i < 4096; i += 256) ((int4*)Wlds)[i] = ((const int4*)Wp)[stage * 4096 + i];
        __syncthreads();
        #pragma unroll
        for (int ksl = 0; ksl < 8; ++ksl) {
            const short* Tm = Ts[stage * 2 + (ksl >> 2)];
            short8 af = *((const short8*)(Tm + rb + (ksl & 3) * 32 + quad * 8));
            #pragma unroll
            for (int nt = 0; nt < 8; ++nt) {
                short8 bf = *((const short8*)(Wlds + ((ksl * 8 + nt) * 64 + lane) * 8));
                acc[nt] = __builtin_amdgcn_mfma_f32_16x16x32_bf16(af, bf, acc[nt], 0, 0, 0);
            }
        }
    }
    // C/D layout: col = lane&15, row = quad*4 + reg
    int col0 = lane & 15;
    int rbase = r0 + quad * 4;
    #pragma unroll
    for (int nt = 0; nt < 8; ++nt) {
        int c = nt * 16 + col0;
        float bv = bias[c];
        #pragma unroll
        for (int rg = 0; rg < 4; ++rg) {
            int r = rbase + rg;
            if (r < M) OUT[(size_t)r * 128 + c] = acc[nt][rg] + bv;
        }
    }
}

// ---------------- BatchNorm ----------------

__global__ __launch_bounds__(256) void k_stats(const float* __restrict__ X, float* __restrict__ S, int N, int act) {
    int col = threadIdx.x & 127, rh = threadIdx.x >> 7;
    int r0 = blockIdx.x * 512;
    int rend = r0 + 512 < N ? r0 + 512 : N;
    float s1 = 0.f, s2 = 0.f;
    for (int r = r0 + rh; r < rend; r += 2) {
        float v = actf(X[(size_t)r * 128 + col], act);
        s1 += v;
        s2 += v * v;
    }
    atomicAdd(&S[col], s1);
    atomicAdd(&S[col + 128], s2);
}

__global__ __launch_bounds__(128) void k_bnfin(const float* __restrict__ S, const float* __restrict__ g,
                                               const float* __restrict__ be, float* __restrict__ AC, int N) {
    int f = threadIdx.x;
    float mu = S[f] / (float)N;
    float var = S[f + 128] / (float)N - mu * mu;
    float rstd = rsqrtf(var + BN_EPS);
    float a = g[f] * rstd;
    AC[f] = a;
    AC[f + 128] = be[f] - mu * a;
}

// read fp32 X, apply act + BN affine, write bf16 (packed pairs)
__global__ __launch_bounds__(256) void k_bnapply(const float* __restrict__ X, const float* __restrict__ AC,
                                                 unsigned* __restrict__ Y, int n4, int act) {
    int i = blockIdx.x * 256 + threadIdx.x;
    if (i >= n4) return;
    float4 v = ((const float4*)X)[i];
    int col = (i * 4) & 127;
    float4 a = *((const float4*)(AC + col));
    float4 c = *((const float4*)(AC + 128 + col));
    v.x = actf(v.x, act) * a.x + c.x;
    v.y = actf(v.y, act) * a.y + c.y;
    v.z = actf(v.z, act) * a.z + c.z;
    v.w = actf(v.w, act) * a.w + c.w;
    uint2 o;
    o.x = pack2bf(v.x, v.y);
    o.y = pack2bf(v.z, v.w);
    ((uint2*)Y)[i] = o;
}

// ---------------- final: L2-normalize rows + project 128->3 ----------------

__global__ __launch_bounds__(256) void k_final(const float* __restrict__ H, const float* __restrict__ Wrep,
                                               const float* __restrict__ brep, float* __restrict__ out, int N) {
    int node = blockIdx.x * 4 + (threadIdx.x >> 6);
    if (node >= N) return;
    int lane = threadIdx.x & 63;
    float2 h = ((const float2*)H)[(size_t)node * 64 + lane];
    int f0 = 2 * lane;
    float nrm = h.x * h.x + h.y * h.y;
    float p0 = h.x * Wrep[f0 * 3 + 0] + h.y * Wrep[(f0 + 1) * 3 + 0];
    float p1 = h.x * Wrep[f0 * 3 + 1] + h.y * Wrep[(f0 + 1) * 3 + 1];
    float p2 = h.x * Wrep[f0 * 3 + 2] + h.y * Wrep[(f0 + 1) * 3 + 2];
    #pragma unroll
    for (int d = 1; d < 64; d <<= 1) {
        nrm += __shfl_xor(nrm, d);
        p0 += __shfl_xor(p0, d);
        p1 += __shfl_xor(p1, d);
        p2 += __shfl_xor(p2, d);
    }
    if (lane == 0) {
        float inv = 1.f / fmaxf(sqrtf(nrm), L2_EPS);
        out[node * 3 + 0] = p0 * inv + brep[0];
        out[node * 3 + 1] = p1 * inv + brep[1];
        out[node * 3 + 2] = p2 * inv + brep[2];
    }
}

// ---------------- host ----------------

extern "C" void kernel_launch(void* const* d_in, const int* in_sizes, int n_in,
                              void* d_out, int out_size, void* d_ws, size_t ws_size,
                              hipStream_t stream) {
    const int N = in_sizes[0] / 3;   // 100000
    const int E = in_sizes[1] / 2;   // 1600000

    const float* x    = (const float*)d_in[0];
    const int*   ei   = (const int*)d_in[1];
    const int* esrc = ei;
    const int* edst = ei + E;
    const float* W1 = (const float*)d_in[2];  const float* b1 = (const float*)d_in[3];
    const float* W2 = (const float*)d_in[4];  const float* b2 = (const float*)d_in[5];
    const float* W3 = (const float*)d_in[6];  const float* b3 = (const float*)d_in[7];
    const float* W4 = (const float*)d_in[8];  const float* b4 = (const float*)d_in[9];
    const float* g1 = (const float*)d_in[10]; const float* be1 = (const float*)d_in[11];
    const float* g2 = (const float*)d_in[12]; const float* be2 = (const float*)d_in[13];
    const float* g3 = (const float*)d_in[14]; const float* be3 = (const float*)d_in[15];
    const float* Wrep = (const float*)d_in[16]; const float* brep = (const float*)d_in[17];
    float* out = (float*)d_out;

    char* w = (char*)d_ws;
    size_t off = 0;
    auto alloc = [&](size_t bytes) { size_t o = off; off = (off + bytes + 255) & ~(size_t)255; return o; };
    int*   cnt    = (int*)(w + alloc((size_t)N * 4));
    int*   rowptr = (int*)(w + alloc((size_t)(N + 1) * 4));
    int*   cursor = (int*)(w + alloc((size_t)N * 4));
    float* dinv   = (float*)(w + alloc((size_t)N * 4));
    int2*  edges  = (int2*)(w + alloc((size_t)E * 8));
    short* Wp     = (short*)(w + alloc(3 * 65536 * 2));
    float* S      = (float*)(w + alloc(256 * 4));
    float* AC     = (float*)(w + alloc(256 * 4));
    float* t1f    = (float*)(w + alloc((size_t)N * 3 * 4));
    float* t2f    = (float*)(w + alloc((size_t)N * 3 * 4));
    float* t3f    = (float*)(w + alloc((size_t)N * 3 * 4));
    short* T0     = (short*)(w + alloc((size_t)N * 128 * 2));  // bf16 feature bufs
    short* T1     = (short*)(w + alloc((size_t)N * 128 * 2));
    short* T2     = (short*)(w + alloc((size_t)N * 128 * 2));
    short* T3     = (short*)(w + alloc((size_t)N * 128 * 2));
    float* OUT    = (float*)(w + alloc((size_t)N * 128 * 4));

    int gE = (E + 255) / 256;
    int gN = (N + 255) / 256;
    int gW = (N + 3) / 4;       // wave-per-node kernels
    int gM = (N + 63) / 64;     // MFMA gemm blocks

    // --- preprocessing ---
    hipMemsetAsync(cnt, 0, (size_t)N * 4, stream);
    k_hist<<<gE, 256, 0, stream>>>(edst, cnt, E);
    k_dinv<<<gN, 256, 0, stream>>>(cnt, dinv, N);
    k_scan<<<1, 1024, 0, stream>>>(cnt, rowptr, cursor, N);
    k_fill<<<gE, 256, 0, stream>>>(esrc, edst, dinv, cursor, edges, E);
    k_packW<<<768, 256, 0, stream>>>(W2, W3, W4, Wp);

    // --- layer 1 (F_in=3, fp32) ---
    k_prop3<<<gN, 256, 0, stream>>>(x, nullptr, t1f, rowptr, edges, 1.f, 0.f, N);
    k_prop3<<<gN, 256, 0, stream>>>(t1f, x, t2f, rowptr, edges, 2.f, -1.f, N);
    k_prop3<<<gN, 256, 0, stream>>>(t2f, t1f, t3f, rowptr, edges, 2.f, -1.f, N);
    k_gemm1<<<(N + 1) / 2, 256, 0, stream>>>(x, t1f, t2f, t3f, W1, b1, OUT, N);
    hipMemsetAsync(S, 0, 256 * 4, stream);
    k_stats<<<(N + 511) / 512, 256, 0, stream>>>(OUT, S, N, 0);
    k_bnfin<<<1, 128, 0, stream>>>(S, g1, be1, AC, N);
    k_bnapply<<<(N * 32 + 255) / 256, 256, 0, stream>>>(OUT, AC, (unsigned*)T0, N * 32, 0);

    // --- layers 2..4 ---
    const float* bs[3]  = {b2, b3, b4};
    const float* gs[3]  = {g2, g3, nullptr};
    const float* bes[3] = {be2, be3, nullptr};
    int acts[3] = {0, 1, 2};  // leaky, relu, none

    for (int l = 0; l < 3; ++l) {
        const unsigned* U0 = (const unsigned*)T0;
        unsigned* U1 = (unsigned*)T1;
        unsigned* U2 = (unsigned*)T2;
        unsigned* U3 = (unsigned*)T3;
        k_prop128<<<gW, 256, 0, stream>>>(U0, nullptr, U1, rowptr, edges, 1.f, 0.f, N);
        k_prop128<<<gW, 256, 0, stream>>>((const unsigned*)U1, U0, U2, rowptr, edges, 2.f, -1.f, N);
        k_prop128<<<gW, 256, 0, stream>>>((const unsigned*)U2, (const unsigned*)U1, U3, rowptr, edges, 2.f, -1.f, N);
        k_gemm512<<<gM, 256, 0, stream>>>(T0, T1, T2, T3, Wp + (size_t)l * 65536, bs[l], OUT, N);

        if (l < 2) {
            hipMemsetAsync(S, 0, 256 * 4, stream);
            k_stats<<<(N + 511) / 512, 256, 0, stream>>>(OUT, S, N, acts[l]);
            k_bnfin<<<1, 128, 0, stream>>>(S, gs[l], bes[l], AC, N);
            k_bnapply<<<(N * 32 + 255) / 256, 256, 0, stream>>>(OUT, AC, (unsigned*)T0, N * 32, acts[l]);
        }
    }

    // --- final: L2 norm + projection ---
    k_final<<<gW, 256, 0, stream>>>(OUT, Wrep, brep, out, N);
}

// Round 4
// 1327.183 us; speedup vs baseline: 1.7437x; 1.1576x over previous
//
#include <hip/hip_runtime.h>
#include <hip/hip_bf16.h>

// ChebConv GNN, N=100000, E=1600000, HID=128, K=4.
// R4: multi-block scan (was 97us single-block), OUT in bf16, BN stats fused
//     into GEMM epilogue, 16-deep gather batching in prop128.

#define HID 128
#define NEG 0.01f
#define BN_EPS 1e-5f
#define L2_EPS 1e-12f

typedef __attribute__((ext_vector_type(8))) short short8;
typedef __attribute__((ext_vector_type(4))) float floatx4;

__device__ __forceinline__ short f2bf(float f) {
    unsigned u = __float_as_uint(f);
    return (short)((u + 0x7fffu + ((u >> 16) & 1u)) >> 16);
}
__device__ __forceinline__ unsigned pack2bf(float x, float y) {
    return (unsigned)(unsigned short)f2bf(x) | ((unsigned)(unsigned short)f2bf(y) << 16);
}
__device__ __forceinline__ float bflo(unsigned u) { return __uint_as_float(u << 16); }
__device__ __forceinline__ float bfhi(unsigned u) { return __uint_as_float(u & 0xffff0000u); }
__device__ __forceinline__ float bf2f(unsigned short h) { return __uint_as_float((unsigned)h << 16); }

__device__ __forceinline__ float actf(float v, int act) {
    if (act == 0) return v >= 0.f ? v : NEG * v;   // leaky_relu
    if (act == 1) return v > 0.f ? v : 0.f;        // relu
    return v;
}

// ---------------- preprocessing ----------------

__global__ __launch_bounds__(256) void k_hist(const int* __restrict__ dst, int* __restrict__ cnt, int E) {
    int e = blockIdx.x * 256 + threadIdx.x;
    if (e < E) atomicAdd(&cnt[dst[e]], 1);
}

// scanA: per-block (1024 elems) sums
__global__ __launch_bounds__(256) void k_scanA(const int* __restrict__ cnt, int* __restrict__ bsum, int n) {
    __shared__ int ws[4];
    int tid = threadIdx.x, lane = tid & 63, wv = tid >> 6;
    int base = blockIdx.x * 1024 + tid * 4;
    int s = 0;
    #pragma unroll
    for (int k = 0; k < 4; ++k) {
        int i = base + k;
        if (i < n) s += cnt[i];
    }
    #pragma unroll
    for (int d = 1; d < 64; d <<= 1) s += __shfl_xor(s, d);
    if (lane == 0) ws[wv] = s;
    __syncthreads();
    if (tid == 0) bsum[blockIdx.x] = ws[0] + ws[1] + ws[2] + ws[3];
}

// scanB: single block, exclusive scan of <=128 block sums; writes rowptr[n] total
__global__ __launch_bounds__(128) void k_scanB(const int* __restrict__ bsum, int* __restrict__ boff,
                                               int* __restrict__ rowptr, int nb, int n) {
    __shared__ int wt[2];
    int tid = threadIdx.x, lane = tid & 63, wv = tid >> 6;
    int v = tid < nb ? bsum[tid] : 0;
    int s = v;
    #pragma unroll
    for (int d = 1; d < 64; d <<= 1) {
        int t = __shfl_up(s, d);
        if (lane >= d) s += t;
    }
    if (lane == 63) wt[wv] = s;
    __syncthreads();
    int excl = s - v + (wv == 1 ? wt[0] : 0);
    if (tid < nb) boff[tid] = excl;
    if (tid == nb - 1) rowptr[n] = excl + v;
}

// scanC: per-block local exclusive scan + block offset -> rowptr, cursor; also dinv
__global__ __launch_bounds__(256) void k_scanC(const int* __restrict__ cnt, const int* __restrict__ boff,
                                               int* __restrict__ rowptr, int* __restrict__ cursor,
                                               float* __restrict__ dinv, int n) {
    __shared__ int wt[4];
    int tid = threadIdx.x, lane = tid & 63, wv = tid >> 6;
    int base = blockIdx.x * 1024 + tid * 4;
    int v[4];
    int tsum = 0;
    #pragma unroll
    for (int k = 0; k < 4; ++k) {
        int i = base + k;
        v[k] = (i < n) ? cnt[i] : 0;
        tsum += v[k];
    }
    int s = tsum;
    #pragma unroll
    for (int d = 1; d < 64; d <<= 1) {
        int t = __shfl_up(s, d);
        if (lane >= d) s += t;
    }
    if (lane == 63) wt[wv] = s;
    __syncthreads();
    int woff = 0;
    for (int j = 0; j < wv; ++j) woff += wt[j];
    int run = boff[blockIdx.x] + woff + (s - tsum);
    #pragma unroll
    for (int k = 0; k < 4; ++k) {
        int i = base + k;
        if (i < n) {
            rowptr[i] = run;
            cursor[i] = run;
            dinv[i] = v[k] > 0 ? rsqrtf((float)v[k]) : 0.f;
            run += v[k];
        }
    }
}

// one interleaved int2 record per edge: {src, norm(as int)}
__global__ __launch_bounds__(256) void k_fill(const int* __restrict__ src, const int* __restrict__ dst,
                                              const float* __restrict__ dinv, int* __restrict__ cursor,
                                              int2* __restrict__ edges, int E) {
    int e = blockIdx.x * 256 + threadIdx.x;
    if (e >= E) return;
    int s = src[e], d = dst[e];
    int pos = atomicAdd(&cursor[d], 1);
    int2 rec;
    rec.x = s;
    rec.y = __float_as_int(-(dinv[s] * dinv[d]));
    edges[pos] = rec;
}

// ---------------- propagation ----------------

// F=3 fp32, one thread per node. out = a*prop(T) + b*prev
__global__ __launch_bounds__(256) void k_prop3(const float* __restrict__ T, const float* __restrict__ prev,
                                               float* __restrict__ out, const int* __restrict__ rowptr,
                                               const int2* __restrict__ edges,
                                               float a, float b, int N) {
    int i = blockIdx.x * 256 + threadIdx.x;
    if (i >= N) return;
    float a0 = 0.f, a1 = 0.f, a2 = 0.f;
    int e1 = rowptr[i + 1];
    for (int e = rowptr[i]; e < e1; ++e) {
        int2 r = edges[e];
        float w = __int_as_float(r.y);
        a0 += w * T[r.x * 3 + 0];
        a1 += w * T[r.x * 3 + 1];
        a2 += w * T[r.x * 3 + 2];
    }
    float r0 = a * a0, r1 = a * a1, r2 = a * a2;
    if (prev) {
        r0 += b * prev[i * 3 + 0];
        r1 += b * prev[i * 3 + 1];
        r2 += b * prev[i * 3 + 2];
    }
    out[i * 3 + 0] = r0;
    out[i * 3 + 1] = r1;
    out[i * 3 + 2] = r2;
}

// F=128 bf16 in/out, fp32 accumulate. One wave per node, 16-deep gather batching.
__global__ __launch_bounds__(256) void k_prop128(const unsigned* __restrict__ T, const unsigned* __restrict__ prev,
                                                 unsigned* __restrict__ out, const int* __restrict__ rowptr,
                                                 const int2* __restrict__ edges,
                                                 float a, float b, int N) {
    int node = blockIdx.x * 4 + (threadIdx.x >> 6);
    if (node >= N) return;
    node = __builtin_amdgcn_readfirstlane(node);  // wave-uniform -> scalar edge metadata loads
    int lane = threadIdx.x & 63;
    int e0 = rowptr[node], e1 = rowptr[node + 1];
    float accx = 0.f, accy = 0.f;
    int e = e0;
    for (; e + 16 <= e1; e += 16) {
        int2 rec[16];
        unsigned t[16];
        #pragma unroll
        for (int j = 0; j < 16; ++j) rec[j] = edges[e + j];
        #pragma unroll
        for (int j = 0; j < 16; ++j) t[j] = T[(size_t)rec[j].x * 64 + lane];
        #pragma unroll
        for (int j = 0; j < 16; ++j) {
            float w = __int_as_float(rec[j].y);
            accx += w * bflo(t[j]);
            accy += w * bfhi(t[j]);
        }
    }
    for (; e + 4 <= e1; e += 4) {
        int2 rec[4];
        unsigned t[4];
        #pragma unroll
        for (int j = 0; j < 4; ++j) rec[j] = edges[e + j];
        #pragma unroll
        for (int j = 0; j < 4; ++j) t[j] = T[(size_t)rec[j].x * 64 + lane];
        #pragma unroll
        for (int j = 0; j < 4; ++j) {
            float w = __int_as_float(rec[j].y);
            accx += w * bflo(t[j]);
            accy += w * bfhi(t[j]);
        }
    }
    for (; e < e1; ++e) {
        int2 r = edges[e];
        float w = __int_as_float(r.y);
        unsigned t0 = T[(size_t)r.x * 64 + lane];
        accx += w * bflo(t0);
        accy += w * bfhi(t0);
    }
    float rx = a * accx, ry = a * accy;
    if (prev) {
        unsigned p = prev[(size_t)node * 64 + lane];
        rx += b * bflo(p);
        ry += b * bfhi(p);
    }
    out[(size_t)node * 64 + lane] = pack2bf(rx, ry);
}

// ---------------- layer-1 dense (K=12 tiny GEMM), bf16 out ----------------

__global__ __launch_bounds__(256) void k_gemm1(const float* __restrict__ x, const float* __restrict__ t1,
                                               const float* __restrict__ t2, const float* __restrict__ t3,
                                               const float* __restrict__ W, const float* __restrict__ b,
                                               unsigned short* __restrict__ OUT, int N) {
    __shared__ float Wl[12 * 128];
    __shared__ float bl[128];
    int tid = threadIdx.x;
    for (int i = tid; i < 1536; i += 256) Wl[i] = W[i];
    if (tid < 128) bl[tid] = b[tid];
    __syncthreads();
    int node = blockIdx.x * 2 + (tid >> 7);
    if (node >= N) return;
    int f = tid & 127;
    float acc = bl[f];
    const float* rows[4] = {x, t1, t2, t3};
    #pragma unroll
    for (int k = 0; k < 4; ++k) {
        const float* r = rows[k] + (size_t)node * 3;
        acc += r[0] * Wl[(k * 3 + 0) * 128 + f];
        acc += r[1] * Wl[(k * 3 + 1) * 128 + f];
        acc += r[2] * Wl[(k * 3 + 2) * 128 + f];
    }
    OUT[(size_t)node * 128 + f] = (unsigned short)f2bf(acc);
}

// ---------------- big GEMM: OUT[M,128] = [T0|T1|T2|T3][M,512] @ Wp[512,128] + b ----------------

// pack all 3 layers' W (each [4,128,128] fp32) into bf16 B-fragment order.
__global__ __launch_bounds__(256) void k_packW(const float* __restrict__ WA, const float* __restrict__ WB,
                                               const float* __restrict__ WC, short* __restrict__ Wp) {
    int gid = blockIdx.x * 256 + threadIdx.x;  // 0..196607
    int L = gid >> 16;
    int idx = gid & 65535;
    int j = idx & 7;
    int lane = (idx >> 3) & 63;
    int rest = idx >> 9;
    int nt = rest & 7;
    int ks = rest >> 3;
    int kk = ks * 32 + (lane >> 4) * 8 + j;
    int c = nt * 16 + (lane & 15);
    const float* W = (L == 0) ? WA : (L == 1) ? WB : WC;
    Wp[gid] = f2bf(W[(size_t)(kk >> 7) * 16384 + (kk & 127) * 128 + c]);
}

// writes bf16 OUT; if doStats, accumulates BN stats of act(out) into S (LDS-reduced)
__global__ __launch_bounds__(256) void k_gemm512(const short* __restrict__ T0, const short* __restrict__ T1,
                                                 const short* __restrict__ T2, const short* __restrict__ T3,
                                                 const short* __restrict__ Wp, const float* __restrict__ bias,
                                                 unsigned short* __restrict__ OUT, float* __restrict__ S,
                                                 int M, int doStats, int act) {
    __shared__ short Wlds[32768];  // 64 KB: half of the [512,128] bf16 weight, fragment order
    int tid = threadIdx.x;
    int lane = tid & 63, wave = tid >> 6;
    int r0 = blockIdx.x * 64 + wave * 16;
    int row = r0 + (lane & 15);
    int quad = lane >> 4;
    int rowc = row < M ? row : M - 1;
    size_t rb = (size_t)rowc * 128;
    const short* Ts[4] = {T0, T1, T2, T3};
    floatx4 acc[8];
    #pragma unroll
    for (int i = 0; i < 8; ++i) { acc[i][0] = 0.f; acc[i][1] = 0.f; acc[i][2] = 0.f; acc[i][3] = 0.f; }
    #pragma unroll
    for (int stage = 0; stage < 2; ++stage) {
        if (stage) __syncthreads();
        for (int i = tid; i < 4096; i += 256) ((int4*)Wlds)[i] = ((const int4*)Wp)[stage * 4096 + i];
        __syncthreads();
        #pragma unroll
        for (int ksl = 0; ksl < 8; ++ksl) {
            const short* Tm = Ts[stage * 2 + (ksl >> 2)];
            short8 af = *((const short8*)(Tm + rb + (ksl & 3) * 32 + quad * 8));
            #pragma unroll
            for (int nt = 0; nt < 8; ++nt) {
                short8 bf = *((const short8*)(Wlds + ((ksl * 8 + nt) * 64 + lane) * 8));
                acc[nt] = __builtin_amdgcn_mfma_f32_16x16x32_bf16(af, bf, acc[nt], 0, 0, 0);
            }
        }
    }
    // C/D layout: col = lane&15, row = quad*4 + reg
    int col0 = lane & 15;
    int rbase = r0 + quad * 4;
    float s1[8], s2[8];
    #pragma unroll
    for (int nt = 0; nt < 8; ++nt) {
        int c = nt * 16 + col0;
        float bv = bias[c];
        s1[nt] = 0.f; s2[nt] = 0.f;
        #pragma unroll
        for (int rg = 0; rg < 4; ++rg) {
            int r = rbase + rg;
            if (r < M) {
                unsigned short h = (unsigned short)f2bf(acc[nt][rg] + bv);
                OUT[(size_t)r * 128 + c] = h;
                float u = actf(bf2f(h), act);
                s1[nt] += u;
                s2[nt] += u * u;
            }
        }
    }
    if (doStats) {
        __syncthreads();                 // all waves done with Wlds
        float* sS = (float*)Wlds;        // reuse LDS for 256 stat slots
        sS[tid] = 0.f;
        __syncthreads();
        #pragma unroll
        for (int nt = 0; nt < 8; ++nt) {
            int c = nt * 16 + col0;
            atomicAdd(&sS[c], s1[nt]);
            atomicAdd(&sS[c + 128], s2[nt]);
        }
        __syncthreads();
        atomicAdd(&S[tid], sS[tid]);
    }
}

// ---------------- BatchNorm (layer 1 stats only; layers 2-3 fused in gemm512) ----------------

__global__ __launch_bounds__(256) void k_stats(const unsigned* __restrict__ X, float* __restrict__ S,
                                               int N, int act) {
    int u = threadIdx.x & 63, rh = threadIdx.x >> 6;
    int r0 = blockIdx.x * 512;
    int rend = r0 + 512 < N ? r0 + 512 : N;
    float s1x = 0.f, s2x = 0.f, s1y = 0.f, s2y = 0.f;
    for (int r = r0 + rh; r < rend; r += 4) {
        unsigned v = X[(size_t)r * 64 + u];
        float a = actf(bflo(v), act), b = actf(bfhi(v), act);
        s1x += a; s2x += a * a;
        s1y += b; s2y += b * b;
    }
    int c = 2 * u;
    atomicAdd(&S[c], s1x);
    atomicAdd(&S[c + 1], s1y);
    atomicAdd(&S[c + 128], s2x);
    atomicAdd(&S[c + 129], s2y);
}

__global__ __launch_bounds__(128) void k_bnfin(const float* __restrict__ S, const float* __restrict__ g,
                                               const float* __restrict__ be, float* __restrict__ AC, int N) {
    int f = threadIdx.x;
    float mu = S[f] / (float)N;
    float var = S[f + 128] / (float)N - mu * mu;
    float rstd = rsqrtf(var + BN_EPS);
    float a = g[f] * rstd;
    AC[f] = a;
    AC[f + 128] = be[f] - mu * a;
}

// read bf16 X (4 feats per thread), apply act + BN affine, write bf16
__global__ __launch_bounds__(256) void k_bnapply(const unsigned* __restrict__ X, const float* __restrict__ AC,
                                                 unsigned* __restrict__ Y, int n4, int act) {
    int i = blockIdx.x * 256 + threadIdx.x;
    if (i >= n4) return;
    uint2 v = ((const uint2*)X)[i];
    int col = (i * 4) & 127;
    float4 a = *((const float4*)(AC + col));
    float4 c = *((const float4*)(AC + 128 + col));
    float vx = actf(bflo(v.x), act) * a.x + c.x;
    float vy = actf(bfhi(v.x), act) * a.y + c.y;
    float vz = actf(bflo(v.y), act) * a.z + c.z;
    float vw = actf(bfhi(v.y), act) * a.w + c.w;
    uint2 o;
    o.x = pack2bf(vx, vy);
    o.y = pack2bf(vz, vw);
    ((uint2*)Y)[i] = o;
}

// ---------------- final: L2-normalize rows + project 128->3 (bf16 H) ----------------

__global__ __launch_bounds__(256) void k_final(const unsigned* __restrict__ H, const float* __restrict__ Wrep,
                                               const float* __restrict__ brep, float* __restrict__ out, int N) {
    int node = blockIdx.x * 4 + (threadIdx.x >> 6);
    if (node >= N) return;
    int lane = threadIdx.x & 63;
    unsigned u = H[(size_t)node * 64 + lane];
    float hx = bflo(u), hy = bfhi(u);
    int f0 = 2 * lane;
    float nrm = hx * hx + hy * hy;
    float p0 = hx * Wrep[f0 * 3 + 0] + hy * Wrep[(f0 + 1) * 3 + 0];
    float p1 = hx * Wrep[f0 * 3 + 1] + hy * Wrep[(f0 + 1) * 3 + 1];
    float p2 = hx * Wrep[f0 * 3 + 2] + hy * Wrep[(f0 + 1) * 3 + 2];
    #pragma unroll
    for (int d = 1; d < 64; d <<= 1) {
        nrm += __shfl_xor(nrm, d);
        p0 += __shfl_xor(p0, d);
        p1 += __shfl_xor(p1, d);
        p2 += __shfl_xor(p2, d);
    }
    if (lane == 0) {
        float inv = 1.f / fmaxf(sqrtf(nrm), L2_EPS);
        out[node * 3 + 0] = p0 * inv + brep[0];
        out[node * 3 + 1] = p1 * inv + brep[1];
        out[node * 3 + 2] = p2 * inv + brep[2];
    }
}

// ---------------- host ----------------

extern "C" void kernel_launch(void* const* d_in, const int* in_sizes, int n_in,
                              void* d_out, int out_size, void* d_ws, size_t ws_size,
                              hipStream_t stream) {
    const int N = in_sizes[0] / 3;   // 100000
    const int E = in_sizes[1] / 2;   // 1600000

    const float* x    = (const float*)d_in[0];
    const int*   ei   = (const int*)d_in[1];
    const int* esrc = ei;
    const int* edst = ei + E;
    const float* W1 = (const float*)d_in[2];  const float* b1 = (const float*)d_in[3];
    const float* W2 = (const float*)d_in[4];  const float* b2 = (const float*)d_in[5];
    const float* W3 = (const float*)d_in[6];  const float* b3 = (const float*)d_in[7];
    const float* W4 = (const float*)d_in[8];  const float* b4 = (const float*)d_in[9];
    const float* g1 = (const float*)d_in[10]; const float* be1 = (const float*)d_in[11];
    const float* g2 = (const float*)d_in[12]; const float* be2 = (const float*)d_in[13];
    const float* g3 = (const float*)d_in[14]; const float* be3 = (const float*)d_in[15];
    const float* Wrep = (const float*)d_in[16]; const float* brep = (const float*)d_in[17];
    float* out = (float*)d_out;

    char* w = (char*)d_ws;
    size_t off = 0;
    auto alloc = [&](size_t bytes) { size_t o = off; off = (off + bytes + 255) & ~(size_t)255; return o; };
    int*   cnt    = (int*)(w + alloc((size_t)N * 4));
    int*   rowptr = (int*)(w + alloc((size_t)(N + 1) * 4));
    int*   cursor = (int*)(w + alloc((size_t)N * 4));
    float* dinv   = (float*)(w + alloc((size_t)N * 4));
    int*   bsum   = (int*)(w + alloc(128 * 4));
    int*   boff   = (int*)(w + alloc(128 * 4));
    int2*  edges  = (int2*)(w + alloc((size_t)E * 8));
    short* Wp     = (short*)(w + alloc(3 * 65536 * 2));
    float* S      = (float*)(w + alloc(256 * 4));
    float* AC     = (float*)(w + alloc(256 * 4));
    float* t1f    = (float*)(w + alloc((size_t)N * 3 * 4));
    float* t2f    = (float*)(w + alloc((size_t)N * 3 * 4));
    float* t3f    = (float*)(w + alloc((size_t)N * 3 * 4));
    short* T0     = (short*)(w + alloc((size_t)N * 128 * 2));  // bf16 feature bufs
    short* T1     = (short*)(w + alloc((size_t)N * 128 * 2));
    short* T2     = (short*)(w + alloc((size_t)N * 128 * 2));
    short* T3     = (short*)(w + alloc((size_t)N * 128 * 2));
    unsigned short* OUT = (unsigned short*)(w + alloc((size_t)N * 128 * 2));  // bf16

    int gE = (E + 255) / 256;
    int gN = (N + 255) / 256;
    int gW = (N + 3) / 4;            // wave-per-node kernels
    int gM = (N + 63) / 64;          // MFMA gemm blocks
    int gS = (N + 1023) / 1024;      // scan blocks (98)

    // --- preprocessing ---
    hipMemsetAsync(cnt, 0, (size_t)N * 4, stream);
    k_hist<<<gE, 256, 0, stream>>>(edst, cnt, E);
    k_scanA<<<gS, 256, 0, stream>>>(cnt, bsum, N);
    k_scanB<<<1, 128, 0, stream>>>(bsum, boff, rowptr, gS, N);
    k_scanC<<<gS, 256, 0, stream>>>(cnt, boff, rowptr, cursor, dinv, N);
    k_fill<<<gE, 256, 0, stream>>>(esrc, edst, dinv, cursor, edges, E);
    k_packW<<<768, 256, 0, stream>>>(W2, W3, W4, Wp);

    // --- layer 1 (F_in=3, fp32) ---
    k_prop3<<<gN, 256, 0, stream>>>(x, nullptr, t1f, rowptr, edges, 1.f, 0.f, N);
    k_prop3<<<gN, 256, 0, stream>>>(t1f, x, t2f, rowptr, edges, 2.f, -1.f, N);
    k_prop3<<<gN, 256, 0, stream>>>(t2f, t1f, t3f, rowptr, edges, 2.f, -1.f, N);
    k_gemm1<<<(N + 1) / 2, 256, 0, stream>>>(x, t1f, t2f, t3f, W1, b1, OUT, N);
    hipMemsetAsync(S, 0, 256 * 4, stream);
    k_stats<<<(N + 511) / 512, 256, 0, stream>>>((const unsigned*)OUT, S, N, 0);
    k_bnfin<<<1, 128, 0, stream>>>(S, g1, be1, AC, N);
    k_bnapply<<<(N * 32 + 255) / 256, 256, 0, stream>>>((const unsigned*)OUT, AC, (unsigned*)T0, N * 32, 0);

    // --- layers 2..4 ---
    const float* bs[3]  = {b2, b3, b4};
    const float* gs[3]  = {g2, g3, nullptr};
    const float* bes[3] = {be2, be3, nullptr};
    int acts[3] = {0, 1, 2};  // leaky, relu, none

    for (int l = 0; l < 3; ++l) {
        const unsigned* U0 = (const unsigned*)T0;
        unsigned* U1 = (unsigned*)T1;
        unsigned* U2 = (unsigned*)T2;
        unsigned* U3 = (unsigned*)T3;
        k_prop128<<<gW, 256, 0, stream>>>(U0, nullptr, U1, rowptr, edges, 1.f, 0.f, N);
        k_prop128<<<gW, 256, 0, stream>>>((const unsigned*)U1, U0, U2, rowptr, edges, 2.f, -1.f, N);
        k_prop128<<<gW, 256, 0, stream>>>((const unsigned*)U2, (const unsigned*)U1, U3, rowptr, edges, 2.f, -1.f, N);
        if (l < 2) hipMemsetAsync(S, 0, 256 * 4, stream);
        k_gemm512<<<gM, 256, 0, stream>>>(T0, T1, T2, T3, Wp + (size_t)l * 65536, bs[l], OUT, S, N,
                                          l < 2 ? 1 : 0, acts[l]);
        if (l < 2) {
            k_bnfin<<<1, 128, 0, stream>>>(S, gs[l], bes[l], AC, N);
            k_bnapply<<<(N * 32 + 255) / 256, 256, 0, stream>>>((const unsigned*)OUT, AC, (unsigned*)T0, N * 32, acts[l]);
        }
    }

    // --- final: L2 norm + projection ---
    k_final<<<gW, 256, 0, stream>>>((const unsigned*)OUT, Wrep, brep, out, N);
}

// Round 5
// 1152.577 us; speedup vs baseline: 2.0079x; 1.1515x over previous
//
#include <hip/hip_runtime.h>
#include <hip/hip_bf16.h>

// ChebConv GNN, N=100000, E=1600000, HID=128, K=4.
// R5: gemm512 rewritten as weight-resident persistent blocks — 512 thr, full
//     128KB weight in LDS staged ONCE, grid=256 (1 block/CU), waves grid-stride
//     over 32-row tiles (2 MFMA row-tiles share each B-fragment ds_read).

#define HID 128
#define NEG 0.01f
#define BN_EPS 1e-5f
#define L2_EPS 1e-12f

typedef __attribute__((ext_vector_type(8))) short short8;
typedef __attribute__((ext_vector_type(4))) float floatx4;

__device__ __forceinline__ short f2bf(float f) {
    unsigned u = __float_as_uint(f);
    return (short)((u + 0x7fffu + ((u >> 16) & 1u)) >> 16);
}
__device__ __forceinline__ unsigned pack2bf(float x, float y) {
    return (unsigned)(unsigned short)f2bf(x) | ((unsigned)(unsigned short)f2bf(y) << 16);
}
__device__ __forceinline__ float bflo(unsigned u) { return __uint_as_float(u << 16); }
__device__ __forceinline__ float bfhi(unsigned u) { return __uint_as_float(u & 0xffff0000u); }
__device__ __forceinline__ float bf2f(unsigned short h) { return __uint_as_float((unsigned)h << 16); }

__device__ __forceinline__ float actf(float v, int act) {
    if (act == 0) return v >= 0.f ? v : NEG * v;   // leaky_relu
    if (act == 1) return v > 0.f ? v : 0.f;        // relu
    return v;
}

// ---------------- preprocessing ----------------

__global__ __launch_bounds__(256) void k_hist(const int* __restrict__ dst, int* __restrict__ cnt, int E) {
    int e = blockIdx.x * 256 + threadIdx.x;
    if (e < E) atomicAdd(&cnt[dst[e]], 1);
}

// scanA: per-block (1024 elems) sums
__global__ __launch_bounds__(256) void k_scanA(const int* __restrict__ cnt, int* __restrict__ bsum, int n) {
    __shared__ int ws[4];
    int tid = threadIdx.x, lane = tid & 63, wv = tid >> 6;
    int base = blockIdx.x * 1024 + tid * 4;
    int s = 0;
    #pragma unroll
    for (int k = 0; k < 4; ++k) {
        int i = base + k;
        if (i < n) s += cnt[i];
    }
    #pragma unroll
    for (int d = 1; d < 64; d <<= 1) s += __shfl_xor(s, d);
    if (lane == 0) ws[wv] = s;
    __syncthreads();
    if (tid == 0) bsum[blockIdx.x] = ws[0] + ws[1] + ws[2] + ws[3];
}

// scanB: single block, exclusive scan of <=128 block sums; writes rowptr[n] total
__global__ __launch_bounds__(128) void k_scanB(const int* __restrict__ bsum, int* __restrict__ boff,
                                               int* __restrict__ rowptr, int nb, int n) {
    __shared__ int wt[2];
    int tid = threadIdx.x, lane = tid & 63, wv = tid >> 6;
    int v = tid < nb ? bsum[tid] : 0;
    int s = v;
    #pragma unroll
    for (int d = 1; d < 64; d <<= 1) {
        int t = __shfl_up(s, d);
        if (lane >= d) s += t;
    }
    if (lane == 63) wt[wv] = s;
    __syncthreads();
    int excl = s - v + (wv == 1 ? wt[0] : 0);
    if (tid < nb) boff[tid] = excl;
    if (tid == nb - 1) rowptr[n] = excl + v;
}

// scanC: per-block local exclusive scan + block offset -> rowptr, cursor; also dinv
__global__ __launch_bounds__(256) void k_scanC(const int* __restrict__ cnt, const int* __restrict__ boff,
                                               int* __restrict__ rowptr, int* __restrict__ cursor,
                                               float* __restrict__ dinv, int n) {
    __shared__ int wt[4];
    int tid = threadIdx.x, lane = tid & 63, wv = tid >> 6;
    int base = blockIdx.x * 1024 + tid * 4;
    int v[4];
    int tsum = 0;
    #pragma unroll
    for (int k = 0; k < 4; ++k) {
        int i = base + k;
        v[k] = (i < n) ? cnt[i] : 0;
        tsum += v[k];
    }
    int s = tsum;
    #pragma unroll
    for (int d = 1; d < 64; d <<= 1) {
        int t = __shfl_up(s, d);
        if (lane >= d) s += t;
    }
    if (lane == 63) wt[wv] = s;
    __syncthreads();
    int woff = 0;
    for (int j = 0; j < wv; ++j) woff += wt[j];
    int run = boff[blockIdx.x] + woff + (s - tsum);
    #pragma unroll
    for (int k = 0; k < 4; ++k) {
        int i = base + k;
        if (i < n) {
            rowptr[i] = run;
            cursor[i] = run;
            dinv[i] = v[k] > 0 ? rsqrtf((float)v[k]) : 0.f;
            run += v[k];
        }
    }
}

// one interleaved int2 record per edge: {src, norm(as int)}
__global__ __launch_bounds__(256) void k_fill(const int* __restrict__ src, const int* __restrict__ dst,
                                              const float* __restrict__ dinv, int* __restrict__ cursor,
                                              int2* __restrict__ edges, int E) {
    int e = blockIdx.x * 256 + threadIdx.x;
    if (e >= E) return;
    int s = src[e], d = dst[e];
    int pos = atomicAdd(&cursor[d], 1);
    int2 rec;
    rec.x = s;
    rec.y = __float_as_int(-(dinv[s] * dinv[d]));
    edges[pos] = rec;
}

// ---------------- propagation ----------------

// F=3 fp32, one thread per node. out = a*prop(T) + b*prev
__global__ __launch_bounds__(256) void k_prop3(const float* __restrict__ T, const float* __restrict__ prev,
                                               float* __restrict__ out, const int* __restrict__ rowptr,
                                               const int2* __restrict__ edges,
                                               float a, float b, int N) {
    int i = blockIdx.x * 256 + threadIdx.x;
    if (i >= N) return;
    float a0 = 0.f, a1 = 0.f, a2 = 0.f;
    int e1 = rowptr[i + 1];
    for (int e = rowptr[i]; e < e1; ++e) {
        int2 r = edges[e];
        float w = __int_as_float(r.y);
        a0 += w * T[r.x * 3 + 0];
        a1 += w * T[r.x * 3 + 1];
        a2 += w * T[r.x * 3 + 2];
    }
    float r0 = a * a0, r1 = a * a1, r2 = a * a2;
    if (prev) {
        r0 += b * prev[i * 3 + 0];
        r1 += b * prev[i * 3 + 1];
        r2 += b * prev[i * 3 + 2];
    }
    out[i * 3 + 0] = r0;
    out[i * 3 + 1] = r1;
    out[i * 3 + 2] = r2;
}

// F=128 bf16 in/out, fp32 accumulate. One wave per node, 16-deep gather batching.
__global__ __launch_bounds__(256) void k_prop128(const unsigned* __restrict__ T, const unsigned* __restrict__ prev,
                                                 unsigned* __restrict__ out, const int* __restrict__ rowptr,
                                                 const int2* __restrict__ edges,
                                                 float a, float b, int N) {
    int node = blockIdx.x * 4 + (threadIdx.x >> 6);
    if (node >= N) return;
    node = __builtin_amdgcn_readfirstlane(node);  // wave-uniform -> scalar edge metadata loads
    int lane = threadIdx.x & 63;
    int e0 = rowptr[node], e1 = rowptr[node + 1];
    float accx = 0.f, accy = 0.f;
    int e = e0;
    for (; e + 16 <= e1; e += 16) {
        int2 rec[16];
        unsigned t[16];
        #pragma unroll
        for (int j = 0; j < 16; ++j) rec[j] = edges[e + j];
        #pragma unroll
        for (int j = 0; j < 16; ++j) t[j] = T[(size_t)rec[j].x * 64 + lane];
        #pragma unroll
        for (int j = 0; j < 16; ++j) {
            float w = __int_as_float(rec[j].y);
            accx += w * bflo(t[j]);
            accy += w * bfhi(t[j]);
        }
    }
    for (; e + 4 <= e1; e += 4) {
        int2 rec[4];
        unsigned t[4];
        #pragma unroll
        for (int j = 0; j < 4; ++j) rec[j] = edges[e + j];
        #pragma unroll
        for (int j = 0; j < 4; ++j) t[j] = T[(size_t)rec[j].x * 64 + lane];
        #pragma unroll
        for (int j = 0; j < 4; ++j) {
            float w = __int_as_float(rec[j].y);
            accx += w * bflo(t[j]);
            accy += w * bfhi(t[j]);
        }
    }
    for (; e < e1; ++e) {
        int2 r = edges[e];
        float w = __int_as_float(r.y);
        unsigned t0 = T[(size_t)r.x * 64 + lane];
        accx += w * bflo(t0);
        accy += w * bfhi(t0);
    }
    float rx = a * accx, ry = a * accy;
    if (prev) {
        unsigned p = prev[(size_t)node * 64 + lane];
        rx += b * bflo(p);
        ry += b * bfhi(p);
    }
    out[(size_t)node * 64 + lane] = pack2bf(rx, ry);
}

// ---------------- layer-1 dense (K=12 tiny GEMM), bf16 out ----------------

__global__ __launch_bounds__(256) void k_gemm1(const float* __restrict__ x, const float* __restrict__ t1,
                                               const float* __restrict__ t2, const float* __restrict__ t3,
                                               const float* __restrict__ W, const float* __restrict__ b,
                                               unsigned short* __restrict__ OUT, int N) {
    __shared__ float Wl[12 * 128];
    __shared__ float bl[128];
    int tid = threadIdx.x;
    for (int i = tid; i < 1536; i += 256) Wl[i] = W[i];
    if (tid < 128) bl[tid] = b[tid];
    __syncthreads();
    int node = blockIdx.x * 2 + (tid >> 7);
    if (node >= N) return;
    int f = tid & 127;
    float acc = bl[f];
    const float* rows[4] = {x, t1, t2, t3};
    #pragma unroll
    for (int k = 0; k < 4; ++k) {
        const float* r = rows[k] + (size_t)node * 3;
        acc += r[0] * Wl[(k * 3 + 0) * 128 + f];
        acc += r[1] * Wl[(k * 3 + 1) * 128 + f];
        acc += r[2] * Wl[(k * 3 + 2) * 128 + f];
    }
    OUT[(size_t)node * 128 + f] = (unsigned short)f2bf(acc);
}

// ---------------- big GEMM: OUT[M,128] = [T0|T1|T2|T3][M,512] @ Wp[512,128] + b ----------------

// pack all 3 layers' W (each [4,128,128] fp32) into bf16 B-fragment order:
// flat = ((ks*8+nt)*64+lane)*8+j -> B[kk = ks*32+(lane>>4)*8+j][c = nt*16+(lane&15)], kk in [0,512)
__global__ __launch_bounds__(256) void k_packW(const float* __restrict__ WA, const float* __restrict__ WB,
                                               const float* __restrict__ WC, short* __restrict__ Wp) {
    int gid = blockIdx.x * 256 + threadIdx.x;  // 0..196607
    int L = gid >> 16;
    int idx = gid & 65535;
    int j = idx & 7;
    int lane = (idx >> 3) & 63;
    int rest = idx >> 9;
    int nt = rest & 7;
    int ks = rest >> 3;
    int kk = ks * 32 + (lane >> 4) * 8 + j;
    int c = nt * 16 + (lane & 15);
    const float* W = (L == 0) ? WA : (L == 1) ? WB : WC;
    Wp[gid] = f2bf(W[(size_t)(kk >> 7) * 16384 + (kk & 127) * 128 + c]);
}

// Weight-resident persistent GEMM: 512 threads, full 128KB weight in LDS (1 block/CU),
// waves grid-stride over 32-row tiles (2 x 16-row MFMA tiles share each B ds_read).
// Writes bf16 OUT; if doStats, accumulates BN stats of act(out) into S.
__global__ __launch_bounds__(512) void k_gemm512(const short* __restrict__ T0, const short* __restrict__ T1,
                                                 const short* __restrict__ T2, const short* __restrict__ T3,
                                                 const short* __restrict__ Wp, const float* __restrict__ bias,
                                                 unsigned short* __restrict__ OUT, float* __restrict__ S,
                                                 int M, int doStats, int act) {
    __shared__ short Wlds[65536];   // 128 KB: full [512,128] bf16 weight, fragment order
    __shared__ float sS[256];
    int tid = threadIdx.x;
    int lane = tid & 63, wave = tid >> 6;
    if (tid < 256) sS[tid] = 0.f;
    for (int i = tid; i < 8192; i += 512) ((int4*)Wlds)[i] = ((const int4*)Wp)[i];
    __syncthreads();

    int quad = lane >> 4;
    int col0 = lane & 15;
    const short* Ts[4] = {T0, T1, T2, T3};
    float s1[8], s2[8];
    #pragma unroll
    for (int i = 0; i < 8; ++i) { s1[i] = 0.f; s2[i] = 0.f; }

    int nt32 = (M + 31) / 32;
    int stride = gridDim.x * 8;
    for (int t = blockIdx.x * 8 + wave; t < nt32; t += stride) {
        int r0 = t * 32;
        int rowa = r0 + col0;
        int rowb = rowa + 16;
        size_t rb0 = (size_t)(rowa < M ? rowa : M - 1) * 128;
        size_t rb1 = (size_t)(rowb < M ? rowb : M - 1) * 128;
        floatx4 acc0[8], acc1[8];
        #pragma unroll
        for (int i = 0; i < 8; ++i) {
            acc0[i][0] = 0.f; acc0[i][1] = 0.f; acc0[i][2] = 0.f; acc0[i][3] = 0.f;
            acc1[i][0] = 0.f; acc1[i][1] = 0.f; acc1[i][2] = 0.f; acc1[i][3] = 0.f;
        }
        #pragma unroll 4
        for (int ks = 0; ks < 16; ++ks) {
            const short* Tm = Ts[ks >> 2];
            int aoff = (ks & 3) * 32 + quad * 8;
            short8 af0 = *((const short8*)(Tm + rb0 + aoff));
            short8 af1 = *((const short8*)(Tm + rb1 + aoff));
            #pragma unroll
            for (int nt = 0; nt < 8; ++nt) {
                short8 bf = *((const short8*)(Wlds + ((ks * 8 + nt) * 64 + lane) * 8));
                acc0[nt] = __builtin_amdgcn_mfma_f32_16x16x32_bf16(af0, bf, acc0[nt], 0, 0, 0);
                acc1[nt] = __builtin_amdgcn_mfma_f32_16x16x32_bf16(af1, bf, acc1[nt], 0, 0, 0);
            }
        }
        // C/D layout: col = lane&15, row = quad*4 + reg
        #pragma unroll
        for (int half = 0; half < 2; ++half) {
            int rbase = r0 + half * 16 + quad * 4;
            #pragma unroll
            for (int nt = 0; nt < 8; ++nt) {
                int c = nt * 16 + col0;
                float bv = bias[c];
                #pragma unroll
                for (int rg = 0; rg < 4; ++rg) {
                    int r = rbase + rg;
                    if (r < M) {
                        float v = (half ? acc1[nt][rg] : acc0[nt][rg]) + bv;
                        unsigned short h = (unsigned short)f2bf(v);
                        OUT[(size_t)r * 128 + c] = h;
                        float u = actf(bf2f(h), act);
                        s1[nt] += u;
                        s2[nt] += u * u;
                    }
                }
            }
        }
    }
    if (doStats) {
        #pragma unroll
        for (int nt = 0; nt < 8; ++nt) {
            int c = nt * 16 + col0;
            atomicAdd(&sS[c], s1[nt]);
            atomicAdd(&sS[c + 128], s2[nt]);
        }
        __syncthreads();
        if (tid < 256) atomicAdd(&S[tid], sS[tid]);
    }
}

// ---------------- BatchNorm (layer 1 stats only; layers 2-3 fused in gemm512) ----------------

__global__ __launch_bounds__(256) void k_stats(const unsigned* __restrict__ X, float* __restrict__ S,
                                               int N, int act) {
    int u = threadIdx.x & 63, rh = threadIdx.x >> 6;
    int r0 = blockIdx.x * 512;
    int rend = r0 + 512 < N ? r0 + 512 : N;
    float s1x = 0.f, s2x = 0.f, s1y = 0.f, s2y = 0.f;
    for (int r = r0 + rh; r < rend; r += 4) {
        unsigned v = X[(size_t)r * 64 + u];
        float a = actf(bflo(v), act), b = actf(bfhi(v), act);
        s1x += a; s2x += a * a;
        s1y += b; s2y += b * b;
    }
    int c = 2 * u;
    atomicAdd(&S[c], s1x);
    atomicAdd(&S[c + 1], s1y);
    atomicAdd(&S[c + 128], s2x);
    atomicAdd(&S[c + 129], s2y);
}

__global__ __launch_bounds__(128) void k_bnfin(const float* __restrict__ S, const float* __restrict__ g,
                                               const float* __restrict__ be, float* __restrict__ AC, int N) {
    int f = threadIdx.x;
    float mu = S[f] / (float)N;
    float var = S[f + 128] / (float)N - mu * mu;
    float rstd = rsqrtf(var + BN_EPS);
    float a = g[f] * rstd;
    AC[f] = a;
    AC[f + 128] = be[f] - mu * a;
}

// read bf16 X (4 feats per thread), apply act + BN affine, write bf16
__global__ __launch_bounds__(256) void k_bnapply(const unsigned* __restrict__ X, const float* __restrict__ AC,
                                                 unsigned* __restrict__ Y, int n4, int act) {
    int i = blockIdx.x * 256 + threadIdx.x;
    if (i >= n4) return;
    uint2 v = ((const uint2*)X)[i];
    int col = (i * 4) & 127;
    float4 a = *((const float4*)(AC + col));
    float4 c = *((const float4*)(AC + 128 + col));
    float vx = actf(bflo(v.x), act) * a.x + c.x;
    float vy = actf(bfhi(v.x), act) * a.y + c.y;
    float vz = actf(bflo(v.y), act) * a.z + c.z;
    float vw = actf(bfhi(v.y), act) * a.w + c.w;
    uint2 o;
    o.x = pack2bf(vx, vy);
    o.y = pack2bf(vz, vw);
    ((uint2*)Y)[i] = o;
}

// ---------------- final: L2-normalize rows + project 128->3 (bf16 H) ----------------

__global__ __launch_bounds__(256) void k_final(const unsigned* __restrict__ H, const float* __restrict__ Wrep,
                                               const float* __restrict__ brep, float* __restrict__ out, int N) {
    int node = blockIdx.x * 4 + (threadIdx.x >> 6);
    if (node >= N) return;
    int lane = threadIdx.x & 63;
    unsigned u = H[(size_t)node * 64 + lane];
    float hx = bflo(u), hy = bfhi(u);
    int f0 = 2 * lane;
    float nrm = hx * hx + hy * hy;
    float p0 = hx * Wrep[f0 * 3 + 0] + hy * Wrep[(f0 + 1) * 3 + 0];
    float p1 = hx * Wrep[f0 * 3 + 1] + hy * Wrep[(f0 + 1) * 3 + 1];
    float p2 = hx * Wrep[f0 * 3 + 2] + hy * Wrep[(f0 + 1) * 3 + 2];
    #pragma unroll
    for (int d = 1; d < 64; d <<= 1) {
        nrm += __shfl_xor(nrm, d);
        p0 += __shfl_xor(p0, d);
        p1 += __shfl_xor(p1, d);
        p2 += __shfl_xor(p2, d);
    }
    if (lane == 0) {
        float inv = 1.f / fmaxf(sqrtf(nrm), L2_EPS);
        out[node * 3 + 0] = p0 * inv + brep[0];
        out[node * 3 + 1] = p1 * inv + brep[1];
        out[node * 3 + 2] = p2 * inv + brep[2];
    }
}

// ---------------- host ----------------

extern "C" void kernel_launch(void* const* d_in, const int* in_sizes, int n_in,
                              void* d_out, int out_size, void* d_ws, size_t ws_size,
                              hipStream_t stream) {
    const int N = in_sizes[0] / 3;   // 100000
    const int E = in_sizes[1] / 2;   // 1600000

    const float* x    = (const float*)d_in[0];
    const int*   ei   = (const int*)d_in[1];
    const int* esrc = ei;
    const int* edst = ei + E;
    const float* W1 = (const float*)d_in[2];  const float* b1 = (const float*)d_in[3];
    const float* W2 = (const float*)d_in[4];  const float* b2 = (const float*)d_in[5];
    const float* W3 = (const float*)d_in[6];  const float* b3 = (const float*)d_in[7];
    const float* W4 = (const float*)d_in[8];  const float* b4 = (const float*)d_in[9];
    const float* g1 = (const float*)d_in[10]; const float* be1 = (const float*)d_in[11];
    const float* g2 = (const float*)d_in[12]; const float* be2 = (const float*)d_in[13];
    const float* g3 = (const float*)d_in[14]; const float* be3 = (const float*)d_in[15];
    const float* Wrep = (const float*)d_in[16]; const float* brep = (const float*)d_in[17];
    float* out = (float*)d_out;

    char* w = (char*)d_ws;
    size_t off = 0;
    auto alloc = [&](size_t bytes) { size_t o = off; off = (off + bytes + 255) & ~(size_t)255; return o; };
    int*   cnt    = (int*)(w + alloc((size_t)N * 4));
    int*   rowptr = (int*)(w + alloc((size_t)(N + 1) * 4));
    int*   cursor = (int*)(w + alloc((size_t)N * 4));
    float* dinv   = (float*)(w + alloc((size_t)N * 4));
    int*   bsum   = (int*)(w + alloc(128 * 4));
    int*   boff   = (int*)(w + alloc(128 * 4));
    int2*  edges  = (int2*)(w + alloc((size_t)E * 8));
    short* Wp     = (short*)(w + alloc(3 * 65536 * 2));
    float* S      = (float*)(w + alloc(256 * 4));
    float* AC     = (float*)(w + alloc(256 * 4));
    float* t1f    = (float*)(w + alloc((size_t)N * 3 * 4));
    float* t2f    = (float*)(w + alloc((size_t)N * 3 * 4));
    float* t3f    = (float*)(w + alloc((size_t)N * 3 * 4));
    short* T0     = (short*)(w + alloc((size_t)N * 128 * 2));  // bf16 feature bufs
    short* T1     = (short*)(w + alloc((size_t)N * 128 * 2));
    short* T2     = (short*)(w + alloc((size_t)N * 128 * 2));
    short* T3     = (short*)(w + alloc((size_t)N * 128 * 2));
    unsigned short* OUT = (unsigned short*)(w + alloc((size_t)N * 128 * 2));  // bf16

    int gE = (E + 255) / 256;
    int gN = (N + 255) / 256;
    int gW = (N + 3) / 4;            // wave-per-node kernels
    int gS = (N + 1023) / 1024;      // scan blocks (98)

    // --- preprocessing ---
    hipMemsetAsync(cnt, 0, (size_t)N * 4, stream);
    k_hist<<<gE, 256, 0, stream>>>(edst, cnt, E);
    k_scanA<<<gS, 256, 0, stream>>>(cnt, bsum, N);
    k_scanB<<<1, 128, 0, stream>>>(bsum, boff, rowptr, gS, N);
    k_scanC<<<gS, 256, 0, stream>>>(cnt, boff, rowptr, cursor, dinv, N);
    k_fill<<<gE, 256, 0, stream>>>(esrc, edst, dinv, cursor, edges, E);
    k_packW<<<768, 256, 0, stream>>>(W2, W3, W4, Wp);

    // --- layer 1 (F_in=3, fp32) ---
    k_prop3<<<gN, 256, 0, stream>>>(x, nullptr, t1f, rowptr, edges, 1.f, 0.f, N);
    k_prop3<<<gN, 256, 0, stream>>>(t1f, x, t2f, rowptr, edges, 2.f, -1.f, N);
    k_prop3<<<gN, 256, 0, stream>>>(t2f, t1f, t3f, rowptr, edges, 2.f, -1.f, N);
    k_gemm1<<<(N + 1) / 2, 256, 0, stream>>>(x, t1f, t2f, t3f, W1, b1, OUT, N);
    hipMemsetAsync(S, 0, 256 * 4, stream);
    k_stats<<<(N + 511) / 512, 256, 0, stream>>>((const unsigned*)OUT, S, N, 0);
    k_bnfin<<<1, 128, 0, stream>>>(S, g1, be1, AC, N);
    k_bnapply<<<(N * 32 + 255) / 256, 256, 0, stream>>>((const unsigned*)OUT, AC, (unsigned*)T0, N * 32, 0);

    // --- layers 2..4 ---
    const float* bs[3]  = {b2, b3, b4};
    const float* gs[3]  = {g2, g3, nullptr};
    const float* bes[3] = {be2, be3, nullptr};
    int acts[3] = {0, 1, 2};  // leaky, relu, none

    for (int l = 0; l < 3; ++l) {
        const unsigned* U0 = (const unsigned*)T0;
        unsigned* U1 = (unsigned*)T1;
        unsigned* U2 = (unsigned*)T2;
        unsigned* U3 = (unsigned*)T3;
        k_prop128<<<gW, 256, 0, stream>>>(U0, nullptr, U1, rowptr, edges, 1.f, 0.f, N);
        k_prop128<<<gW, 256, 0, stream>>>((const unsigned*)U1, U0, U2, rowptr, edges, 2.f, -1.f, N);
        k_prop128<<<gW, 256, 0, stream>>>((const unsigned*)U2, (const unsigned*)U1, U3, rowptr, edges, 2.f, -1.f, N);
        if (l < 2) hipMemsetAsync(S, 0, 256 * 4, stream);
        k_gemm512<<<256, 512, 0, stream>>>(T0, T1, T2, T3, Wp + (size_t)l * 65536, bs[l], OUT, S, N,
                                           l < 2 ? 1 : 0, acts[l]);
        if (l < 2) {
            k_bnfin<<<1, 128, 0, stream>>>(S, gs[l], bes[l], AC, N);
            k_bnapply<<<(N * 32 + 255) / 256, 256, 0, stream>>>((const unsigned*)OUT, AC, (unsigned*)T0, N * 32, acts[l]);
        }
    }

    // --- final: L2 norm + projection ---
    k_final<<<gW, 256, 0, stream>>>((const unsigned*)OUT, Wrep, brep, out, N);
}